// Round 9
// baseline (12486.950 us; speedup 1.0000x reference)
//
#include <hip/hip_runtime.h>

// ---------------------------------------------------------------------------
// TTS forward on MI355X.
//   embed -> conv1(+BN+ReLU) -> conv2(+BN+ReLU) -> persistent biLSTM encoder
//   -> W_eff fold -> persistent 800-step decoder LSTM + lagging projection.
// Round 12 (= round 11 resubmit, hardened): TAGGED DATAFLOW exchange.
// Each 8B atomic word = 2 fp16 values + 32-bit tag (epoch<<11 | step).
// Consumers load slots speculatively and retry only words whose tag
// mismatches -> no producer vmcnt ack, no flags, no flag polls. Epoch
// counter (persistent, bumped per launch) kills cross-replay staleness,
// enabling small L3-warm rings (dec 64, enc 16 slots). All-to-all dataflow
// bounds inter-block skew to 1 step -> ring overwrite-safe. Proj blocks
// publish progress; producers backpressure (slack 62 steps).
// ---------------------------------------------------------------------------

typedef float f4 __attribute__((ext_vector_type(4)));
typedef _Float16 h8 __attribute__((ext_vector_type(8)));
typedef _Float16 half_t;
typedef unsigned u4 __attribute__((ext_vector_type(4)));
typedef unsigned long long u64;

#define B_    32
#define LTXT  256
#define TMEL  800
#define EE    512
#define HH    512
#define DD    1024
#define MM    128
#define NROWS 8192          // B_*LTXT
#define GATE_OFF 3276800    // B_*TMEL*MM
#define MASK_OFF 3302400    // + B_*TMEL

#define RING_D 64           // decoder ring slots (128KB each, tagged words)
#define RING_E 16           // encoder ring slots
#define HOP    13           // coprime with 64 and 16

// workspace offsets (bytes)
#define WS_PROG       0ull            // proj progress[16] (zeroed, 4KB pad)
#define WS_EPOCT      4096ull         // u64 persistent epoch counter (NOT zeroed)
#define WS_EPOCH      4160ull         // u32 current epoch (written by k_epoch)
#define WS_HENC       8192ull         // RING_E * 131072 = 2 MiB (slot0 zeroed)
#define WS_HD         2105344ull      // RING_D * 131072 = 8 MiB
#define WS_BUFX       10493952ull     // 8 MiB
#define WS_BUFY       18882560ull     // 8 MiB
#define WS_CONVF      27271168ull     // 16 MiB (reused by WEFF/W0 after convs)
#define WS_WEFF       27271168ull
#define WS_W0         35659776ull
#define WS_WP1        44048384ull
#define WS_WP2        45621248ull
#define WS_WIHP       47194112ull     // 4 MiB
#define WS_WHHP       51388416ull     // 4 MiB
#define WS_BSUM       55582720ull
#define WS_BEFF       55599104ull
#define WS_B0         55615488ull
#define WS_MEAN       55631872ull
#define WS_RSTD       55633920ull
#define WS_PROJW      55635968ull
#define WS_PROJG      55898112ull
#define WS_CEL        55930880ull
// total ~56.1 MB

__device__ __forceinline__ float sigm(float x) { return 1.f / (1.f + __expf(-x)); }
__device__ __forceinline__ float tanh_f(float x) {
    float e = __expf(2.f * x);
    return 1.f - 2.f / (e + 1.f);
}
__device__ __forceinline__ unsigned mktag(unsigned ep, int t) {
    return (ep << 11) | (unsigned)t;
}

// return-less atomic swap: commits at coherence point, atomically visible
__device__ __forceinline__ void st_atom64(void* p, u64 v) {
    asm volatile("global_atomic_swap_x2 %0, %1, off" :: "v"(p), "v"(v) : "memory");
}
__device__ __forceinline__ void st_atom32(unsigned* p, unsigned v) {
    asm volatile("global_atomic_swap %0, %1, off" :: "v"(p), "v"(v) : "memory");
}
// coherent 16B load: served at the coherence point
__device__ __forceinline__ u4 ld_l3(const void* p) {
    u4 r;
    asm volatile("global_load_dwordx4 %0, %1, off sc0 sc1" : "=v"(r) : "v"(p) : "memory");
    return r;
}
__device__ __forceinline__ void wait_vm0() {
    asm volatile("s_waitcnt vmcnt(0)" ::: "memory");
    __builtin_amdgcn_sched_barrier(0);
}

// ---------------- small prep kernels ----------------

__global__ void k_epoch(unsigned long long* ctr, unsigned* cur) {
    unsigned long long e = *ctr + 1ull;
    *ctr = e;
    *cur = (unsigned)e;
}

__global__ void k_embed(const int* __restrict__ x, const float* __restrict__ emb,
                        half_t* __restrict__ out) {
    int row = blockIdx.x;
    int tok = x[row];
    const float* e = emb + (size_t)tok * EE;
    half_t* o = out + (size_t)row * EE;
    for (int c = threadIdx.x; c < EE; c += blockDim.x) o[c] = (half_t)e[c];
}

__global__ void k_packconvw(const float* __restrict__ w, half_t* __restrict__ wp) {
    int idx = blockIdx.x * 256 + threadIdx.x;
    if (idx >= 3 * EE * EE) return;
    int s = idx / (EE * EE);
    int rem = idx - s * EE * EE;
    int eo = rem >> 9, ei = rem & 511;
    wp[idx] = (half_t)w[(size_t)eo * (EE * 3) + ei * 3 + s];
}

__global__ __launch_bounds__(256) void k_conv(const half_t* __restrict__ A,
                                              const half_t* __restrict__ Wp,
                                              const float* __restrict__ bias,
                                              float* __restrict__ out) {
    const int nt = blockIdx.x, et = blockIdx.y;
    const int tid = threadIdx.x;
    const int wv = tid >> 6, l = tid & 63, quad = l >> 4, lo = l & 15;
    const int rowA = nt * 64 + wv * 16 + lo;
    const int eo = et * 16 + lo;
    f4 acc = {0.f, 0.f, 0.f, 0.f};
    for (int s = 0; s < 3; ++s) {
        int lsp = (rowA & 255) + s - 1;
        bool valid = (lsp >= 0) && (lsp < 256);
        int rs = rowA + s - 1;
        rs = rs < 0 ? 0 : (rs > NROWS - 1 ? NROWS - 1 : rs);
        const half_t* ab = A + (size_t)rs * EE;
        const half_t* wb = Wp + ((size_t)s * EE + eo) * EE;
#pragma unroll 4
        for (int ks = 0; ks < 16; ++ks) {
            h8 a = {0, 0, 0, 0, 0, 0, 0, 0};
            if (valid) a = *(const h8*)(ab + ks * 32 + quad * 8);
            h8 b = *(const h8*)(wb + ks * 32 + quad * 8);
            acc = __builtin_amdgcn_mfma_f32_16x16x32_f16(a, b, acc, 0, 0, 0);
        }
    }
    const int orow = nt * 64 + wv * 16 + quad * 4;
    const float bv = bias[eo];
#pragma unroll
    for (int r = 0; r < 4; ++r) out[(size_t)(orow + r) * EE + eo] = acc[r] + bv;
}

__global__ __launch_bounds__(256) void k_bnstats(const float* __restrict__ x,
                                                 float* __restrict__ mean,
                                                 float* __restrict__ rstd) {
    const int c = blockIdx.x;
    float s = 0.f, ss = 0.f;
    for (int n = threadIdx.x; n < NROWS; n += 256) {
        float v = x[(size_t)n * EE + c];
        s += v; ss += v * v;
    }
#pragma unroll
    for (int off = 32; off > 0; off >>= 1) { s += __shfl_down(s, off); ss += __shfl_down(ss, off); }
    __shared__ float as[4], ass[4];
    int wv = threadIdx.x >> 6;
    if ((threadIdx.x & 63) == 0) { as[wv] = s; ass[wv] = ss; }
    __syncthreads();
    if (threadIdx.x == 0) {
        float S = as[0] + as[1] + as[2] + as[3];
        float SS = ass[0] + ass[1] + ass[2] + ass[3];
        float m = S / (float)NROWS;
        float var = SS / (float)NROWS - m * m;
        mean[c] = m;
        rstd[c] = rsqrtf(var + 1e-5f);
    }
}

__global__ void k_bnapply(const float* __restrict__ x, const float* __restrict__ mean,
                          const float* __restrict__ rstd, const float* __restrict__ g,
                          const float* __restrict__ beta, half_t* __restrict__ out) {
    int idx = blockIdx.x * 256 + threadIdx.x;
    if (idx >= NROWS * EE) return;
    int c = idx & (EE - 1);
    float v = (x[idx] - mean[c]) * rstd[c] * g[c] + beta[c];
    out[idx] = (half_t)(v > 0.f ? v : 0.f);
}

__global__ void k_packrec(const float* __restrict__ src, half_t* __restrict__ dst,
                          int Hdim, int kshift, int total) {
    int idx = blockIdx.x * 256 + threadIdx.x;
    if (idx >= total) return;
    int p = idx >> kshift;
    int k = idx & ((1 << kshift) - 1);
    int he = p >> 2, g = p & 3;
    dst[idx] = (half_t)src[((size_t)g * Hdim + he) * (size_t)(1 << kshift) + k];
}

__global__ void k_bsumenc(const float* __restrict__ bf, const float* __restrict__ bhf,
                          const float* __restrict__ bb, const float* __restrict__ bhb,
                          float* __restrict__ bsum) {
    int p = blockIdx.x * 256 + threadIdx.x;
    if (p >= 4096) return;
    int dir = p >> 11, pp = p & 2047;
    int he = pp >> 2, g = pp & 3;
    int row = g * HH + he;
    bsum[p] = dir ? (bb[row] + bhb[row]) : (bf[row] + bhf[row]);
}

__global__ __launch_bounds__(256) void k_weff(const float* __restrict__ dwhh,
                                              const float* __restrict__ dwih,
                                              const float* __restrict__ projw,
                                              half_t* __restrict__ weff,
                                              half_t* __restrict__ w0) {
    int row = blockIdx.x;
    int k = blockIdx.y * 256 + threadIdx.x;
    float v = dwhh[(size_t)row * DD + k];
    float acc = v;
    for (int m = 0; m < MM; ++m) acc += dwih[(size_t)row * MM + m] * projw[(size_t)m * DD + k];
    int p = ((row & (DD - 1)) << 2) | (row >> 10);
    weff[(size_t)p * DD + k] = (half_t)acc;
    w0[(size_t)p * DD + k] = (half_t)v;
}

__global__ void k_bdec(const float* __restrict__ dbih, const float* __restrict__ dbhh,
                       const float* __restrict__ dwih, const float* __restrict__ projb,
                       float* __restrict__ beff, float* __restrict__ b0) {
    int p = blockIdx.x * 256 + threadIdx.x;
    if (p >= 4096) return;
    int he = p >> 2, g = p & 3;
    int row = g * DD + he;
    float bb = dbih[row] + dbhh[row];
    float acc = bb;
    for (int m = 0; m < MM; ++m) acc += dwih[(size_t)row * MM + m] * projb[m];
    b0[p] = bb;
    beff[p] = acc;
}

__global__ void k_cast(const float* __restrict__ src, half_t* __restrict__ dst, int n) {
    int idx = blockIdx.x * 256 + threadIdx.x;
    if (idx < n) dst[idx] = (half_t)src[idx];
}

__global__ void k_projg(const float* __restrict__ gw, half_t* __restrict__ pg) {
    int idx = blockIdx.x * 256 + threadIdx.x;
    if (idx >= 16 * DD) return;
    int row = idx >> 10, k = idx & (DD - 1);
    pg[idx] = (half_t)(row == 0 ? gw[k] : 0.f);
}

__global__ void k_mask(const int* __restrict__ lens, float* __restrict__ out) {
    int idx = blockIdx.x * 256 + threadIdx.x;
    if (idx >= B_ * TMEL) return;
    int b = idx / TMEL, t = idx - b * TMEL;
    out[MASK_OFF + idx] = (t > lens[b]) ? 1.f : 0.f;
}

// ---------------- persistent bidirectional encoder LSTM ----------------
// 64 blocks x 512 thr. dir=j>>5, sub=j&31 owns 16 h-elems. Weights in VGPRs.
// Exchange: tagged words. Producer wave0: 4 one-way 8B atomics/lane (2 fp16
// + tag each). Consumer: speculative 8x16B coherent loads + per-word tag
// verify/retry. Ring RING_E=16 slots x 128KB; epoch kills replay staleness.
__global__ __launch_bounds__(512) void k_enc(const half_t* __restrict__ X,
                                             const half_t* __restrict__ wihp,
                                             const half_t* __restrict__ whhp,
                                             const float* __restrict__ bsum,
                                             const int* __restrict__ lens,
                                             u64* __restrict__ hencT,   // ring [RING_E][2 dir][8192 words]
                                             u64* __restrict__ hdT,     // dec ring (slot 0 written here)
                                             float* __restrict__ cel,   // [32][1024]
                                             const unsigned* __restrict__ epc) {
    const int j = blockIdx.x;
    const int dir = j >> 5, sub = j & 31;
    const int tid = threadIdx.x;
    const int wv = tid >> 6, l = tid & 63, quad = l >> 4, lo = l & 15;
    const int rg = wv >> 1, bh = wv & 1;
    const int bfr = bh * 16 + lo;
    const int ue = tid >> 5, ub = tid & 31;

    __shared__ half_t s_hd[32 * 520];
    __shared__ float s_g[32][65];
    __shared__ float s_c[16][32];
    __shared__ float s_h[16][32];
    __shared__ half_t s_hh[16][32];
    __shared__ int s_len[32];

    if (tid < 32) s_len[tid] = lens[tid];
    s_c[ue][ub] = 0.f;
    s_h[ue][ub] = 0.f;
    const unsigned ep = epc[0];

    const int pr = dir * 2048 + sub * 64 + rg * 16 + lo;
    const half_t* wih_b = wihp + (size_t)pr * 512;
    const half_t* whh_b = whhp + (size_t)pr * 512;
    const float bias_n = bsum[pr];

    h8 wihreg[16], whhreg[16];
#pragma unroll
    for (int ks = 0; ks < 16; ++ks) {
        wihreg[ks] = *(const h8*)(wih_b + ks * 32 + quad * 8);
        whhreg[ks] = *(const h8*)(whh_b + ks * 32 + quad * 8);
    }

    int sp = 0, sn = HOP;
    __syncthreads();

    for (int t = 0; t < 256; ++t) {
        // speculative coherent loads of this dir's half-slot (8 x 16B)
        const char* base = (const char*)hencT + (size_t)sp * 131072 + (size_t)dir * 65536;
        u4 tp[8];
#pragma unroll
        for (int i = 0; i < 8; ++i)
            tp[i] = ld_l3(base + ((size_t)tid + i * 512) * 16);

        // x-part MFMA overlaps the loads
        const int lb = s_len[bfr];
        int tt = (dir == 0) ? t : (lb - 1 - t);
        tt = tt < 0 ? 0 : tt;
        const half_t* xr = X + ((size_t)bfr * 256 + tt) * 512;
        f4 accA = {0.f, 0.f, 0.f, 0.f}, accB = {0.f, 0.f, 0.f, 0.f};
#pragma unroll
        for (int ks = 0; ks < 16; ++ks) {
            h8 a = *(const h8*)(xr + ks * 32 + quad * 8);
            accA = __builtin_amdgcn_mfma_f32_16x16x32_f16(a, wihreg[ks], accA, 0, 0, 0);
        }

        wait_vm0();
        // verify tags (slot 0 at t==0 is zeroed => skip)
        if (t > 0) {
            const unsigned want = mktag(ep, t);
#pragma unroll
            for (int i = 0; i < 8; ++i) {
                while (tp[i][1] != want || tp[i][3] != want) {
                    __builtin_amdgcn_s_sleep(4);
                    tp[i] = ld_l3(base + ((size_t)tid + i * 512) * 16);
                    wait_vm0();
                }
            }
        }
        // stage values into LDS: pair pp -> batch=pp>>7, elems (pp&127)*4
#pragma unroll
        for (int i = 0; i < 8; ++i) {
            int pp = tid + i * 512;
            u64 v = ((u64)tp[i][2] << 32) | (u64)tp[i][0];
            *(u64*)(s_hd + (size_t)(pp >> 7) * 520 + (pp & 127) * 4) = v;
        }
        __syncthreads();

#pragma unroll
        for (int ks = 0; ks < 16; ++ks) {
            h8 a = *(const h8*)(s_hd + (size_t)bfr * 520 + ks * 32 + quad * 8);
            accB = __builtin_amdgcn_mfma_f32_16x16x32_f16(a, whhreg[ks], accB, 0, 0, 0);
        }
        const int bm = bh * 16 + quad * 4, cm = rg * 16 + lo;
#pragma unroll
        for (int r = 0; r < 4; ++r) s_g[bm + r][cm] = accA[r] + accB[r] + bias_n;
        __syncthreads();
        {
            float gi = s_g[ub][ue * 4 + 0], gf = s_g[ub][ue * 4 + 1];
            float gg = s_g[ub][ue * 4 + 2], go = s_g[ub][ue * 4 + 3];
            float cn = sigm(gf) * s_c[ue][ub] + sigm(gi) * tanh_f(gg);
            float hn = sigm(go) * tanh_f(cn);
            if (t < s_len[ub]) { s_c[ue][ub] = cn; s_h[ue][ub] = hn; }
            s_hh[ue][ub] = (half_t)s_h[ue][ub];
        }
        __syncthreads();
        if (tid < 64 && t < 255) {
            // one-way tagged atomics; no ack, no flags
            int b2 = tid >> 1, hv = tid & 1;
            const u64 tagw = (u64)mktag(ep, t + 1) << 32;
            u64* dstw = hencT + (size_t)sn * 16384 + (size_t)dir * 8192
                        + (size_t)b2 * 256 + sub * 8 + hv * 4;
#pragma unroll
            for (int k = 0; k < 4; ++k) {
                int e = hv * 8 + 2 * k;
                union { half_t h[2]; unsigned u; } pk;
                pk.h[0] = s_hh[e + 0][b2]; pk.h[1] = s_hh[e + 1][b2];
                st_atom64(dstw + k, tagw | (u64)pk.u);
            }
        }
        if (t < 255) { sp = sn; sn += HOP; if (sn >= RING_E) sn -= RING_E; }
    }
    // epilogue: decoder ring slot 0 (word layout; dec t==1 skips tag check)
    if (!(ue & 1)) {
        union { half_t h[2]; unsigned u; } pk;
        pk.h[0] = (half_t)s_h[ue][ub]; pk.h[1] = (half_t)s_h[ue + 1][ub];
        hdT[(size_t)ub * 512 + dir * 256 + sub * 8 + (ue >> 1)] = (u64)pk.u;
    }
    cel[(size_t)ub * 1024 + dir * 512 + sub * 16 + ue] = s_c[ue][ub];
}

// ---------------- persistent decoder LSTM + projection consumers ----------
// Grid 73 x 512 thr. Blocks 0..63: core (16 h-elems each, Weff in VGPRs).
// Tagged-word exchange: producer 4 one-way atomics/lane; consumer 16x16B
// speculative loads + tag verify/retry. Ring RING_D=64 slots; proj blocks
// (64..72) publish progress; producers backpressure prog >= t-62 before
// overwrite (prefetched; spin only on failure).
__global__ __launch_bounds__(512) void k_dec(const half_t* __restrict__ Weff,
                                             const half_t* __restrict__ W0,
                                             const float* __restrict__ beff,
                                             const float* __restrict__ b0,
                                             const half_t* __restrict__ projwb,
                                             const half_t* __restrict__ projg,
                                             const float* __restrict__ projb,
                                             const float* __restrict__ gateb,
                                             const int* __restrict__ mlens,
                                             const float* __restrict__ cel,
                                             u64* __restrict__ hdT,     // ring [RING_D][16384 words]
                                             float* __restrict__ out,
                                             unsigned* __restrict__ prog, // [16] proj progress
                                             const unsigned* __restrict__ epc) {
    const int j = blockIdx.x;
    const int tid = threadIdx.x;
    const int wv = tid >> 6, l = tid & 63, quad = l >> 4, lo = l & 15;
    const unsigned ep = epc[0];

    __shared__ half_t s_hd[32 * 1032];
    __shared__ float s_g[32][65];
    __shared__ float s_c[16][32];
    __shared__ half_t s_hh[16][32];
    __shared__ int s_len[32];

    if (j < 64) {
        // ---------------- core recurrence block ----------------
        const int rg = wv >> 1, bh = wv & 1;
        const int bfr = bh * 16 + lo;
        const int ue = tid >> 5, ub = tid & 31;

        s_c[ue][ub] = cel[(size_t)ub * 1024 + j * 16 + ue];
        const int pr = j * 64 + rg * 16 + lo;
        const float biasE = beff[pr], bias0 = b0[pr];
        const half_t* wbE = Weff + (size_t)pr * 1024;
        const half_t* wb0 = W0 + (size_t)pr * 1024;

        h8 wreg[32];
#pragma unroll
        for (int ks = 0; ks < 32; ++ks)
            wreg[ks] = *(const h8*)(wbE + ks * 32 + quad * 8);

        int sp = 0, sn = HOP;
        __syncthreads();

        for (int t = 1; t <= TMEL; ++t) {
            // speculative coherent loads of the slot (16 x 16B) + prog prefetch
            const char* base = (const char*)hdT + (size_t)sp * 131072;
            u4 tp[16];
#pragma unroll
            for (int i = 0; i < 16; ++i)
                tp[i] = ld_l3(base + ((size_t)tid + i * 512) * 16);
            unsigned pv = 0x7FFFFFFFu;
            if (tid < 9)
                pv = __hip_atomic_load(prog + tid, __ATOMIC_RELAXED, __HIP_MEMORY_SCOPE_AGENT);
            wait_vm0();
            if (t > 1) {
                const unsigned want = mktag(ep, t - 1);
#pragma unroll
                for (int i = 0; i < 16; ++i) {
                    while (tp[i][1] != want || tp[i][3] != want) {
                        __builtin_amdgcn_s_sleep(4);
                        tp[i] = ld_l3(base + ((size_t)tid + i * 512) * 16);
                        wait_vm0();
                    }
                }
            }
            // stage: pair pp -> batch=pp>>8, elems (pp&255)*4
#pragma unroll
            for (int i = 0; i < 16; ++i) {
                int pp = tid + i * 512;
                u64 v = ((u64)tp[i][2] << 32) | (u64)tp[i][0];
                *(u64*)(s_hd + (size_t)(pp >> 8) * 1032 + (pp & 255) * 4) = v;
            }
            __syncthreads();

            const half_t* ar = s_hd + (size_t)bfr * 1032 + quad * 8;
            f4 acc = {0.f, 0.f, 0.f, 0.f}, acc2 = {0.f, 0.f, 0.f, 0.f};
            if (t == 1) {
#pragma unroll 8
                for (int ks = 0; ks < 32; ks += 2) {
                    h8 a0 = *(const h8*)(ar + ks * 32);
                    h8 a1 = *(const h8*)(ar + ks * 32 + 32);
                    acc = __builtin_amdgcn_mfma_f32_16x16x32_f16(a0, *(const h8*)(wb0 + ks * 32 + quad * 8), acc, 0, 0, 0);
                    acc2 = __builtin_amdgcn_mfma_f32_16x16x32_f16(a1, *(const h8*)(wb0 + ks * 32 + 32 + quad * 8), acc2, 0, 0, 0);
                }
            } else {
#pragma unroll
                for (int ks = 0; ks < 32; ks += 2) {
                    h8 a0 = *(const h8*)(ar + ks * 32);
                    h8 a1 = *(const h8*)(ar + ks * 32 + 32);
                    acc = __builtin_amdgcn_mfma_f32_16x16x32_f16(a0, wreg[ks], acc, 0, 0, 0);
                    acc2 = __builtin_amdgcn_mfma_f32_16x16x32_f16(a1, wreg[ks + 1], acc2, 0, 0, 0);
                }
            }
            const float bn = (t == 1) ? bias0 : biasE;
            const int bm = bh * 16 + quad * 4, cm = rg * 16 + lo;
#pragma unroll
            for (int r = 0; r < 4; ++r) s_g[bm + r][cm] = acc[r] + acc2[r] + bn;
            __syncthreads();
            {
                float gi = s_g[ub][ue * 4 + 0], gf = s_g[ub][ue * 4 + 1];
                float gg = s_g[ub][ue * 4 + 2], go = s_g[ub][ue * 4 + 3];
                float cn = sigm(gf) * s_c[ue][ub] + sigm(gi) * tanh_f(gg);
                s_c[ue][ub] = cn;
                s_hh[ue][ub] = (half_t)(sigm(go) * tanh_f(cn));
            }
            __syncthreads();
            if (tid < 64) {
                // backpressure: don't overwrite a slot proj may still need
                if (t >= 63) {
                    const int need = t - 62;
                    while (!__all((int)pv >= need)) {
                        __builtin_amdgcn_s_sleep(8);
                        if (tid < 9)
                            pv = __hip_atomic_load(prog + tid, __ATOMIC_RELAXED,
                                                   __HIP_MEMORY_SCOPE_AGENT);
                    }
                }
                int b2 = tid >> 1, hv = tid & 1;
                const u64 tagw = (u64)mktag(ep, t) << 32;
                u64* dstw = hdT + (size_t)sn * 16384 + (size_t)b2 * 512 + j * 8 + hv * 4;
#pragma unroll
                for (int k = 0; k < 4; ++k) {
                    int e = hv * 8 + 2 * k;
                    union { half_t h[2]; unsigned u; } pk;
                    pk.h[0] = s_hh[e + 0][b2]; pk.h[1] = s_hh[e + 1][b2];
                    st_atom64(dstw + k, tagw | (u64)pk.u);
                }
            }
            sp = sn; sn += HOP; if (sn >= RING_D) sn -= RING_D;
        }
    } else {
        // ---------------- lagging projection consumer block ----------------
        const int pj = j - 64;
        const bool meld = (pj < 8);
        const bool duty = (wv < 2);
        const int bh2 = wv & 1;
        const half_t* pw = meld ? (projwb + (size_t)(pj * 16 + lo) * 1024)
                                : (projg + (size_t)lo * 1024);
        const float biasP = meld ? projb[pj * 16 + lo] : gateb[0];

        h8 pwreg[32];
        if (duty) {
#pragma unroll
            for (int ks = 0; ks < 32; ++ks)
                pwreg[ks] = *(const h8*)(pw + ks * 32 + quad * 8);
        }
        if (tid < 32) s_len[tid] = mlens[tid];

        int spP = HOP;
        __syncthreads();

        for (int t = 1; t <= TMEL; ++t) {
            // speculative loads of slot containing h_t + tag verify
            const char* base = (const char*)hdT + (size_t)spP * 131072;
            u4 tp[16];
#pragma unroll
            for (int i = 0; i < 16; ++i)
                tp[i] = ld_l3(base + ((size_t)tid + i * 512) * 16);
            wait_vm0();
            {
                const unsigned want = mktag(ep, t);
#pragma unroll
                for (int i = 0; i < 16; ++i) {
                    while (tp[i][1] != want || tp[i][3] != want) {
                        __builtin_amdgcn_s_sleep(4);
                        tp[i] = ld_l3(base + ((size_t)tid + i * 512) * 16);
                        wait_vm0();
                    }
                }
            }
#pragma unroll
            for (int i = 0; i < 16; ++i) {
                int pp = tid + i * 512;
                u64 v = ((u64)tp[i][2] << 32) | (u64)tp[i][0];
                *(u64*)(s_hd + (size_t)(pp >> 8) * 1032 + (pp & 255) * 4) = v;
            }
            __syncthreads();

            if (duty) {
                const half_t* ar = s_hd + (size_t)(bh2 * 16 + lo) * 1032 + quad * 8;
                f4 accm = {0.f, 0.f, 0.f, 0.f}, accm2 = {0.f, 0.f, 0.f, 0.f};
#pragma unroll
                for (int ks = 0; ks < 32; ks += 2) {
                    h8 a0 = *(const h8*)(ar + ks * 32);
                    h8 a1 = *(const h8*)(ar + ks * 32 + 32);
                    accm = __builtin_amdgcn_mfma_f32_16x16x32_f16(a0, pwreg[ks], accm, 0, 0, 0);
                    accm2 = __builtin_amdgcn_mfma_f32_16x16x32_f16(a1, pwreg[ks + 1], accm2, 0, 0, 0);
                }
                accm[0] += accm2[0]; accm[1] += accm2[1];
                accm[2] += accm2[2]; accm[3] += accm2[3];
                const int pos = t - 1;
                if (meld) {
#pragma unroll
                    for (int r = 0; r < 4; ++r) {
                        int b = bh2 * 16 + quad * 4 + r;
                        float v = accm[r] + biasP;
                        if (pos > s_len[b]) v = 0.f;
                        __builtin_nontemporal_store(v,
                            &out[(size_t)b * (TMEL * MM) + (size_t)pos * MM + pj * 16 + lo]);
                    }
                } else if (lo == 0) {
#pragma unroll
                    for (int r = 0; r < 4; ++r) {
                        int b = bh2 * 16 + quad * 4 + r;
                        float v = accm[r] + biasP;
                        if (pos > s_len[b]) v = 1000.f;
                        __builtin_nontemporal_store(v, &out[GATE_OFF + (size_t)b * TMEL + pos]);
                    }
                }
            }
            __syncthreads();   // s_hd fully consumed
            if (tid == 0) st_atom32(prog + pj, (unsigned)t);   // publish progress
            spP += HOP; if (spP >= RING_D) spP -= RING_D;
        }
    }
}

// ---------------------------------------------------------------------------

extern "C" void kernel_launch(void* const* d_in, const int* in_sizes, int n_in,
                              void* d_out, int out_size, void* d_ws, size_t ws_size,
                              hipStream_t stream) {
    const int* x = (const int*)d_in[0];
    const int* tlens = (const int*)d_in[1];
    const int* mlens = (const int*)d_in[3];
    const float* emb = (const float*)d_in[4];
    const float* c1w = (const float*)d_in[5];
    const float* c1b = (const float*)d_in[6];
    const float* bn1g = (const float*)d_in[7];
    const float* bn1b = (const float*)d_in[8];
    const float* c2w = (const float*)d_in[9];
    const float* c2b = (const float*)d_in[10];
    const float* bn2g = (const float*)d_in[11];
    const float* bn2b = (const float*)d_in[12];
    const float* wihf = (const float*)d_in[13];
    const float* whhf = (const float*)d_in[14];
    const float* bihf = (const float*)d_in[15];
    const float* bhhf = (const float*)d_in[16];
    const float* wihb = (const float*)d_in[17];
    const float* whhb = (const float*)d_in[18];
    const float* bihb = (const float*)d_in[19];
    const float* bhhb = (const float*)d_in[20];
    const float* dwih = (const float*)d_in[21];
    const float* dwhh = (const float*)d_in[22];
    const float* dbih = (const float*)d_in[23];
    const float* dbhh = (const float*)d_in[24];
    const float* projw = (const float*)d_in[25];
    const float* projb = (const float*)d_in[26];
    const float* gatew = (const float*)d_in[27];
    const float* gateb = (const float*)d_in[28];
    float* out = (float*)d_out;
    char* ws = (char*)d_ws;

    unsigned* prog = (unsigned*)(ws + WS_PROG);
    unsigned long long* epoct = (unsigned long long*)(ws + WS_EPOCT);
    unsigned* epc = (unsigned*)(ws + WS_EPOCH);
    u64* hencT = (u64*)(ws + WS_HENC);
    u64* hdT = (u64*)(ws + WS_HD);
    half_t* bufX = (half_t*)(ws + WS_BUFX);
    half_t* bufY = (half_t*)(ws + WS_BUFY);
    float* convf = (float*)(ws + WS_CONVF);
    half_t* weff = (half_t*)(ws + WS_WEFF);
    half_t* w0 = (half_t*)(ws + WS_W0);
    half_t* wp1 = (half_t*)(ws + WS_WP1);
    half_t* wp2 = (half_t*)(ws + WS_WP2);
    float* meanb = (float*)(ws + WS_MEAN);
    float* rstdb = (float*)(ws + WS_RSTD);
    half_t* wihp = (half_t*)(ws + WS_WIHP);
    half_t* whhp = (half_t*)(ws + WS_WHHP);
    float* bsum = (float*)(ws + WS_BSUM);
    float* beff = (float*)(ws + WS_BEFF);
    float* b0 = (float*)(ws + WS_B0);
    half_t* projwb = (half_t*)(ws + WS_PROJW);
    half_t* projg = (half_t*)(ws + WS_PROJG);
    float* cel = (float*)(ws + WS_CEL);

    // zero proj progress + encoder ring slot 0; bump epoch
    hipMemsetAsync(ws + WS_PROG, 0, 4096, stream);
    hipMemsetAsync(ws + WS_HENC, 0, 131072, stream);
    k_epoch<<<1, 1, 0, stream>>>(epoct, epc);

    // front-end
    k_embed<<<NROWS, 256, 0, stream>>>(x, emb, bufX);
    k_packconvw<<<(3 * EE * EE + 255) / 256, 256, 0, stream>>>(c1w, wp1);
    k_conv<<<dim3(128, 32), 256, 0, stream>>>(bufX, wp1, c1b, convf);
    k_bnstats<<<EE, 256, 0, stream>>>(convf, meanb, rstdb);
    k_bnapply<<<(NROWS * EE) / 256, 256, 0, stream>>>(convf, meanb, rstdb, bn1g, bn1b, bufY);
    k_packconvw<<<(3 * EE * EE + 255) / 256, 256, 0, stream>>>(c2w, wp2);
    k_conv<<<dim3(128, 32), 256, 0, stream>>>(bufY, wp2, c2b, convf);
    k_bnstats<<<EE, 256, 0, stream>>>(convf, meanb, rstdb);
    k_bnapply<<<(NROWS * EE) / 256, 256, 0, stream>>>(convf, meanb, rstdb, bn2g, bn2b, bufX);

    // encoder weight prep
    const int encTot = 2048 * 512;
    k_packrec<<<(encTot + 255) / 256, 256, 0, stream>>>(wihf, wihp, HH, 9, encTot);
    k_packrec<<<(encTot + 255) / 256, 256, 0, stream>>>(wihb, wihp + encTot, HH, 9, encTot);
    k_packrec<<<(encTot + 255) / 256, 256, 0, stream>>>(whhf, whhp, HH, 9, encTot);
    k_packrec<<<(encTot + 255) / 256, 256, 0, stream>>>(whhb, whhp + encTot, HH, 9, encTot);
    k_bsumenc<<<16, 256, 0, stream>>>(bihf, bhhf, bihb, bhhb, bsum);

    // persistent bidirectional encoder (writes dec ring slot 0 + cel)
    k_enc<<<64, 512, 0, stream>>>(bufX, wihp, whhp, bsum, tlens, hencT, hdT, cel, epc);

    // decoder weight prep (into retired convf region)
    k_weff<<<dim3(4096, 4), 256, 0, stream>>>(dwhh, dwih, projw, weff, w0);
    k_bdec<<<16, 256, 0, stream>>>(dbih, dbhh, dwih, projb, beff, b0);
    k_cast<<<(MM * DD + 255) / 256, 256, 0, stream>>>(projw, projwb, MM * DD);
    k_projg<<<(16 * DD + 255) / 256, 256, 0, stream>>>(gatew, projg);

    // persistent decoder (64 core + 9 projection blocks)
    k_dec<<<73, 512, 0, stream>>>(weff, w0, beff, b0, projwb, projg, projb, gateb,
                                  mlens, cel, hdT, out, prog, epc);

    // mask output
    k_mask<<<(B_ * TMEL + 255) / 256, 256, 0, stream>>>(mlens, out);

    (void)in_sizes; (void)n_in; (void)out_size; (void)ws_size;
}

// Round 10
// 4481.564 us; speedup vs baseline: 2.7863x; 2.7863x over previous
//
#include <hip/hip_runtime.h>

// ---------------------------------------------------------------------------
// TTS forward on MI355X.
//   embed -> conv1(+BN+ReLU) -> conv2(+BN+ReLU) -> persistent biLSTM encoder
//   -> W_eff fold -> persistent 800-step decoder LSTM + projection blocks
// Round 13: BATCH-SPLIT decoder. Batch items are independent -> decoder
// splits into 2 independent exchange domains of 16 batch items each:
// 32 core blocks + 1 mel + 1 gate block per domain (grid 68). Each core
// block owns 32 h-elems x 16 batch; per-wave work identical to R7
// (32 MFMAs, 128 weight VGPRs, 1 tile of 16 rows x 16 batch). Exchange
// machinery = R7 verbatim (atomic-swap data, vmcnt ack on single store
// wave, flag fan-out to private mailboxes, poll-wave -> barrier ->
// contiguous coop load, never-reused 801-slot rings). Halves slot size,
// fan-out, straggler pool, poll width. Encoder unchanged.
// ---------------------------------------------------------------------------

typedef float f4 __attribute__((ext_vector_type(4)));
typedef _Float16 h8 __attribute__((ext_vector_type(8)));
typedef _Float16 half_t;
typedef unsigned long long u64;

#define B_    32
#define LTXT  256
#define TMEL  800
#define EE    512
#define HH    512
#define DD    1024
#define MM    128
#define NROWS 8192          // B_*LTXT
#define GATE_OFF 3276800    // B_*TMEL*MM
#define MASK_OFF 3302400    // + B_*TMEL

#define RING_D 801          // decoder ring slots per group (32KB each, never reused)
#define RING_E 257          // encoder ring slots
#define HOP    13           // coprime with both

// workspace offsets (bytes)
#define WS_MBE        0ull             // enc mailboxes: 64 consumers x 64 u32 = 16 KiB
#define WS_MBD        16384ull         // dec mailboxes: 2 groups x 34 x 64 u32 (32 KiB rsvd)
#define WS_HENC       49152ull         // RING_E * 65536
#define WS_ZERO_BYTES 114688ull        // mailboxes + henc slot 0
#define WS_HD         16891904ull      // 2 groups * RING_D * 32768 = 52,494,336
#define WS_BUFX       69386240ull      // 8 MiB
#define WS_BUFY       77774848ull      // 8 MiB
#define WS_CONVF      86163456ull      // 16 MiB (reused by WEFF/W0 after convs)
#define WS_WEFF       86163456ull
#define WS_W0         94552064ull
#define WS_WP1        102940672ull
#define WS_WP2        104513536ull
#define WS_WIHP       106086400ull     // 4 MiB
#define WS_WHHP       110280704ull     // 4 MiB
#define WS_BSUM       114475008ull
#define WS_BEFF       114491392ull
#define WS_B0         114507776ull
#define WS_MEAN       114524160ull
#define WS_RSTD       114526208ull
#define WS_PROJW      114528256ull
#define WS_PROJG      114790400ull
#define WS_CEL        114823168ull
// total ~114.95 MB

__device__ __forceinline__ float sigm(float x) { return 1.f / (1.f + __expf(-x)); }
__device__ __forceinline__ float tanh_f(float x) {
    float e = __expf(2.f * x);
    return 1.f - 2.f / (e + 1.f);
}

// return-less atomic swap: executes at coherence point, line stays L3-resident
__device__ __forceinline__ void st_atom64(void* p, u64 v) {
    asm volatile("global_atomic_swap_x2 %0, %1, off" :: "v"(p), "v"(v) : "memory");
}
__device__ __forceinline__ void st_atom32(unsigned* p, unsigned v) {
    asm volatile("global_atomic_swap %0, %1, off" :: "v"(p), "v"(v) : "memory");
}

// ---------------- small prep kernels ----------------

__global__ void k_embed(const int* __restrict__ x, const float* __restrict__ emb,
                        half_t* __restrict__ out) {
    int row = blockIdx.x;
    int tok = x[row];
    const float* e = emb + (size_t)tok * EE;
    half_t* o = out + (size_t)row * EE;
    for (int c = threadIdx.x; c < EE; c += blockDim.x) o[c] = (half_t)e[c];
}

__global__ void k_packconvw(const float* __restrict__ w, half_t* __restrict__ wp) {
    int idx = blockIdx.x * 256 + threadIdx.x;
    if (idx >= 3 * EE * EE) return;
    int s = idx / (EE * EE);
    int rem = idx - s * EE * EE;
    int eo = rem >> 9, ei = rem & 511;
    wp[idx] = (half_t)w[(size_t)eo * (EE * 3) + ei * 3 + s];
}

__global__ __launch_bounds__(256) void k_conv(const half_t* __restrict__ A,
                                              const half_t* __restrict__ Wp,
                                              const float* __restrict__ bias,
                                              float* __restrict__ out) {
    const int nt = blockIdx.x, et = blockIdx.y;
    const int tid = threadIdx.x;
    const int wv = tid >> 6, l = tid & 63, quad = l >> 4, lo = l & 15;
    const int rowA = nt * 64 + wv * 16 + lo;
    const int eo = et * 16 + lo;
    f4 acc = {0.f, 0.f, 0.f, 0.f};
    for (int s = 0; s < 3; ++s) {
        int lsp = (rowA & 255) + s - 1;
        bool valid = (lsp >= 0) && (lsp < 256);
        int rs = rowA + s - 1;
        rs = rs < 0 ? 0 : (rs > NROWS - 1 ? NROWS - 1 : rs);
        const half_t* ab = A + (size_t)rs * EE;
        const half_t* wb = Wp + ((size_t)s * EE + eo) * EE;
#pragma unroll 4
        for (int ks = 0; ks < 16; ++ks) {
            h8 a = {0, 0, 0, 0, 0, 0, 0, 0};
            if (valid) a = *(const h8*)(ab + ks * 32 + quad * 8);
            h8 b = *(const h8*)(wb + ks * 32 + quad * 8);
            acc = __builtin_amdgcn_mfma_f32_16x16x32_f16(a, b, acc, 0, 0, 0);
        }
    }
    const int orow = nt * 64 + wv * 16 + quad * 4;
    const float bv = bias[eo];
#pragma unroll
    for (int r = 0; r < 4; ++r) out[(size_t)(orow + r) * EE + eo] = acc[r] + bv;
}

__global__ __launch_bounds__(256) void k_bnstats(const float* __restrict__ x,
                                                 float* __restrict__ mean,
                                                 float* __restrict__ rstd) {
    const int c = blockIdx.x;
    float s = 0.f, ss = 0.f;
    for (int n = threadIdx.x; n < NROWS; n += 256) {
        float v = x[(size_t)n * EE + c];
        s += v; ss += v * v;
    }
#pragma unroll
    for (int off = 32; off > 0; off >>= 1) { s += __shfl_down(s, off); ss += __shfl_down(ss, off); }
    __shared__ float as[4], ass[4];
    int wv = threadIdx.x >> 6;
    if ((threadIdx.x & 63) == 0) { as[wv] = s; ass[wv] = ss; }
    __syncthreads();
    if (threadIdx.x == 0) {
        float S = as[0] + as[1] + as[2] + as[3];
        float SS = ass[0] + ass[1] + ass[2] + ass[3];
        float m = S / (float)NROWS;
        float var = SS / (float)NROWS - m * m;
        mean[c] = m;
        rstd[c] = rsqrtf(var + 1e-5f);
    }
}

__global__ void k_bnapply(const float* __restrict__ x, const float* __restrict__ mean,
                          const float* __restrict__ rstd, const float* __restrict__ g,
                          const float* __restrict__ beta, half_t* __restrict__ out) {
    int idx = blockIdx.x * 256 + threadIdx.x;
    if (idx >= NROWS * EE) return;
    int c = idx & (EE - 1);
    float v = (x[idx] - mean[c]) * rstd[c] * g[c] + beta[c];
    out[idx] = (half_t)(v > 0.f ? v : 0.f);
}

__global__ void k_packrec(const float* __restrict__ src, half_t* __restrict__ dst,
                          int Hdim, int kshift, int total) {
    int idx = blockIdx.x * 256 + threadIdx.x;
    if (idx >= total) return;
    int p = idx >> kshift;
    int k = idx & ((1 << kshift) - 1);
    int he = p >> 2, g = p & 3;
    dst[idx] = (half_t)src[((size_t)g * Hdim + he) * (size_t)(1 << kshift) + k];
}

__global__ void k_bsumenc(const float* __restrict__ bf, const float* __restrict__ bhf,
                          const float* __restrict__ bb, const float* __restrict__ bhb,
                          float* __restrict__ bsum) {
    int p = blockIdx.x * 256 + threadIdx.x;
    if (p >= 4096) return;
    int dir = p >> 11, pp = p & 2047;
    int he = pp >> 2, g = pp & 3;
    int row = g * HH + he;
    bsum[p] = dir ? (bb[row] + bhb[row]) : (bf[row] + bhf[row]);
}

__global__ __launch_bounds__(256) void k_weff(const float* __restrict__ dwhh,
                                              const float* __restrict__ dwih,
                                              const float* __restrict__ projw,
                                              half_t* __restrict__ weff,
                                              half_t* __restrict__ w0) {
    int row = blockIdx.x;
    int k = blockIdx.y * 256 + threadIdx.x;
    float v = dwhh[(size_t)row * DD + k];
    float acc = v;
    for (int m = 0; m < MM; ++m) acc += dwih[(size_t)row * MM + m] * projw[(size_t)m * DD + k];
    int p = ((row & (DD - 1)) << 2) | (row >> 10);
    weff[(size_t)p * DD + k] = (half_t)acc;
    w0[(size_t)p * DD + k] = (half_t)v;
}

__global__ void k_bdec(const float* __restrict__ dbih, const float* __restrict__ dbhh,
                       const float* __restrict__ dwih, const float* __restrict__ projb,
                       float* __restrict__ beff, float* __restrict__ b0) {
    int p = blockIdx.x * 256 + threadIdx.x;
    if (p >= 4096) return;
    int he = p >> 2, g = p & 3;
    int row = g * DD + he;
    float bb = dbih[row] + dbhh[row];
    float acc = bb;
    for (int m = 0; m < MM; ++m) acc += dwih[(size_t)row * MM + m] * projb[m];
    b0[p] = bb;
    beff[p] = acc;
}

__global__ void k_cast(const float* __restrict__ src, half_t* __restrict__ dst, int n) {
    int idx = blockIdx.x * 256 + threadIdx.x;
    if (idx < n) dst[idx] = (half_t)src[idx];
}

__global__ void k_projg(const float* __restrict__ gw, half_t* __restrict__ pg) {
    int idx = blockIdx.x * 256 + threadIdx.x;
    if (idx >= 16 * DD) return;
    int row = idx >> 10, k = idx & (DD - 1);
    pg[idx] = (half_t)(row == 0 ? gw[k] : 0.f);
}

__global__ void k_mask(const int* __restrict__ lens, float* __restrict__ out) {
    int idx = blockIdx.x * 256 + threadIdx.x;
    if (idx >= B_ * TMEL) return;
    int b = idx / TMEL, t = idx - b * TMEL;
    out[MASK_OFF + idx] = (t > lens[b]) ? 1.f : 0.f;
}

// ---------------- persistent bidirectional encoder LSTM ----------------
// 64 blocks x 512 thr (unchanged from R7). dir=j>>5, sub=j&31 owns 16
// h-elems. Weights in VGPRs. Store: wave 0, two 8B atomic swaps/lane,
// vmcnt ack, lanes<32 fan one flag atomic per same-dir consumer.
// Poll: wave 1. Epilogue writes dec ring slot 0 in the GROUPED layout:
// group g2=ub>>4, [batch&15][1024].
__global__ __launch_bounds__(512) void k_enc(const half_t* __restrict__ X,
                                             const half_t* __restrict__ wihp,
                                             const half_t* __restrict__ whhp,
                                             const float* __restrict__ bsum,
                                             const int* __restrict__ lens,
                                             half_t* __restrict__ henc,   // ring [RING_E][2][32][512]
                                             half_t* __restrict__ hd,     // dec rings base
                                             float* __restrict__ cel,     // [32][1024]
                                             unsigned* __restrict__ mbE) { // [64 consumers][64]
    const int j = blockIdx.x;
    const int dir = j >> 5, sub = j & 31;
    const int tid = threadIdx.x;
    const int wv = tid >> 6, l = tid & 63, quad = l >> 4, lo = l & 15;
    const int rg = wv >> 1, bh = wv & 1;
    const int bfr = bh * 16 + lo;
    const int ue = tid >> 5, ub = tid & 31;

    __shared__ half_t s_hd[32 * 520];
    __shared__ float s_g[32][65];
    __shared__ float s_c[16][32];
    __shared__ float s_h[16][32];
    __shared__ half_t s_hh[16][32];
    __shared__ int s_len[32];

    if (tid < 32) s_len[tid] = lens[tid];
    s_c[ue][ub] = 0.f;
    s_h[ue][ub] = 0.f;

    const int pr = dir * 2048 + sub * 64 + rg * 16 + lo;
    const half_t* wih_b = wihp + (size_t)pr * 512;
    const half_t* whh_b = whhp + (size_t)pr * 512;
    const float bias_n = bsum[pr];

    h8 wihreg[16], whhreg[16];
#pragma unroll
    for (int ks = 0; ks < 16; ++ks) {
        wihreg[ks] = *(const h8*)(wih_b + ks * 32 + quad * 8);
        whhreg[ks] = *(const h8*)(whh_b + ks * 32 + quad * 8);
    }

    int sp = 0, sn = HOP;
    __syncthreads();

    for (int t = 0; t < 256; ++t) {
        // wait for all producers of slot sp (slot 0 pre-zeroed => skip)
        if (t > 0) {
            if (tid >= 64 && tid < 96) {
                const unsigned want = (unsigned)t;
                const unsigned* fp = mbE + (size_t)(dir * 32 + sub) * 64 + (tid - 64);
                while (__hip_atomic_load(fp, __ATOMIC_RELAXED, __HIP_MEMORY_SCOPE_AGENT) < want)
                    __builtin_amdgcn_s_sleep(1);
            }
            __syncthreads();
        }

        // cooperative cached loads of this dir's half-slot
        const half_t* src = henc + (size_t)sp * 32768 + (size_t)dir * 16384;
        h8 tmp0 = *(const h8*)(src + (size_t)(tid + 0 * 512) * 8);
        h8 tmp1 = *(const h8*)(src + (size_t)(tid + 1 * 512) * 8);
        h8 tmp2 = *(const h8*)(src + (size_t)(tid + 2 * 512) * 8);
        h8 tmp3 = *(const h8*)(src + (size_t)(tid + 3 * 512) * 8);

        // x-part MFMA overlaps the h loads
        const int lb = s_len[bfr];
        int tt = (dir == 0) ? t : (lb - 1 - t);
        tt = tt < 0 ? 0 : tt;
        const half_t* xr = X + ((size_t)bfr * 256 + tt) * 512;
        f4 accA = {0.f, 0.f, 0.f, 0.f}, accB = {0.f, 0.f, 0.f, 0.f};
#pragma unroll
        for (int ks = 0; ks < 16; ++ks) {
            h8 a = *(const h8*)(xr + ks * 32 + quad * 8);
            accA = __builtin_amdgcn_mfma_f32_16x16x32_f16(a, wihreg[ks], accA, 0, 0, 0);
        }

        // stage h into LDS
        {
            int c0 = tid;
            *(h8*)(s_hd + (size_t)(c0 >> 6) * 520 + (c0 & 63) * 8) = tmp0;
            int c1 = tid + 512;
            *(h8*)(s_hd + (size_t)(c1 >> 6) * 520 + (c1 & 63) * 8) = tmp1;
            int c2 = tid + 1024;
            *(h8*)(s_hd + (size_t)(c2 >> 6) * 520 + (c2 & 63) * 8) = tmp2;
            int c3 = tid + 1536;
            *(h8*)(s_hd + (size_t)(c3 >> 6) * 520 + (c3 & 63) * 8) = tmp3;
        }
        __syncthreads();

#pragma unroll
        for (int ks = 0; ks < 16; ++ks) {
            h8 a = *(const h8*)(s_hd + (size_t)bfr * 520 + ks * 32 + quad * 8);
            accB = __builtin_amdgcn_mfma_f32_16x16x32_f16(a, whhreg[ks], accB, 0, 0, 0);
        }
        const int bm = bh * 16 + quad * 4, cm = rg * 16 + lo;
#pragma unroll
        for (int r = 0; r < 4; ++r) s_g[bm + r][cm] = accA[r] + accB[r] + bias_n;
        __syncthreads();
        {
            float gi = s_g[ub][ue * 4 + 0], gf = s_g[ub][ue * 4 + 1];
            float gg = s_g[ub][ue * 4 + 2], go = s_g[ub][ue * 4 + 3];
            float cn = sigm(gf) * s_c[ue][ub] + sigm(gi) * tanh_f(gg);
            float hn = sigm(go) * tanh_f(cn);
            if (t < s_len[ub]) { s_c[ue][ub] = cn; s_h[ue][ub] = hn; }
            s_hh[ue][ub] = (half_t)s_h[ue][ub];
        }
        __syncthreads();
        if (tid < 64 && t < 255) {
            int b2 = tid >> 1, e8 = (tid & 1) * 8;
            union { half_t h[8]; u64 u[2]; } pk;
#pragma unroll
            for (int i = 0; i < 8; ++i) pk.h[i] = s_hh[e8 + i][b2];
            half_t* dst = henc + (size_t)sn * 32768 + (size_t)dir * 16384
                          + (size_t)b2 * 512 + sub * 16 + e8;
            st_atom64(dst, pk.u[0]);
            st_atom64(dst + 4, pk.u[1]);
            asm volatile("s_waitcnt vmcnt(0)");
            if (tid < 32)
                st_atom32(mbE + ((size_t)(dir * 32 + tid) * 64 + sub), (unsigned)(t + 1));
        }
        if (t < 255) { sp = sn; sn += HOP; if (sn >= RING_E) sn -= RING_E; }
    }
    // epilogue: write dec ring slot 0, grouped layout [g][slot0][b&15][1024]
    {
        int g2 = ub >> 4, b = ub & 15;
        hd[(size_t)g2 * ((size_t)RING_D * 16384) + (size_t)b * 1024
           + dir * 512 + sub * 16 + ue] = (half_t)s_h[ue][ub];
    }
    cel[(size_t)ub * 1024 + dir * 512 + sub * 16 + ue] = s_c[ue][ub];
}

// ---------------- persistent decoder LSTM (batch-split) -------------------
// Grid 68 x 512 thr. Two independent groups (batch 16 each):
//   Blocks 0..63: core; g=j>>5, jj=j&31 owns h-elems [32jj,32jj+32) for the
//     group's 16 batch items. 8 waves, 1 tile (16 rows x 16 batch) each,
//     32 MFMAs, Weff in VGPRs. Slot = [16 batch][1024] fp16 = 32KB.
//     Store: wave 0, 2 x 8B atomics/lane; flags fanned to 34 consumers.
//     Poll: wave 1 lanes<32.
//   Blocks 64..67: per group, mel block (all 128 mel rows) + gate block.
__global__ __launch_bounds__(512) void k_dec(const half_t* __restrict__ Weff,
                                             const half_t* __restrict__ W0,
                                             const float* __restrict__ beff,
                                             const float* __restrict__ b0,
                                             const half_t* __restrict__ projwb,
                                             const half_t* __restrict__ projg,
                                             const float* __restrict__ projb,
                                             const float* __restrict__ gateb,
                                             const int* __restrict__ mlens,
                                             const float* __restrict__ cel,
                                             half_t* __restrict__ hd,   // [2][RING_D][16][1024]
                                             float* __restrict__ out,
                                             unsigned* __restrict__ mbD) { // [2][34][64]
    const int j = blockIdx.x;
    const int tid = threadIdx.x;
    const int wv = tid >> 6, l = tid & 63, quad = l >> 4, lo = l & 15;

    __shared__ half_t s_hd[16 * 1032];
    __shared__ float s_g[16][129];
    __shared__ float s_c[32][16];
    __shared__ half_t s_hh[32][16];
    __shared__ int s_len[32];

    if (j < 64) {
        // ---------------- core recurrence block ----------------
        const int g = j >> 5, jj = j & 31;
        half_t* hdG = hd + (size_t)g * ((size_t)RING_D * 16384);
        unsigned* mbG = mbD + (size_t)g * 34 * 64;
        const int ue = tid >> 4;   // h-elem in block [0,32)
        const int ub = tid & 15;   // batch in group [0,16)

        s_c[ue][ub] = cel[(size_t)(g * 16 + ub) * 1024 + jj * 32 + ue];
        const int pr = jj * 128 + wv * 16 + lo;
        const float biasE = beff[pr], bias0 = b0[pr];
        const half_t* wbE = Weff + (size_t)pr * 1024;
        const half_t* wb0 = W0 + (size_t)pr * 1024;

        h8 wreg[32];
#pragma unroll
        for (int ks = 0; ks < 32; ++ks)
            wreg[ks] = *(const h8*)(wbE + ks * 32 + quad * 8);

        int sp = 0, sn = HOP;
        __syncthreads();

        for (int t = 1; t <= TMEL; ++t) {
            // wait for all 32 producers of slot sp (t==1: slot 0 from k_enc)
            if (t > 1) {
                if (tid >= 64 && tid < 96) {
                    const unsigned want = (unsigned)(t - 1);
                    const unsigned* fp = mbG + (size_t)jj * 64 + (tid - 64);
                    while (__hip_atomic_load(fp, __ATOMIC_RELAXED, __HIP_MEMORY_SCOPE_AGENT) < want)
                        __builtin_amdgcn_s_sleep(1);
                }
                __syncthreads();
            }

            // cooperative cached load of the 32KB slot (4 x 16B per thread)
            {
                const half_t* src = hdG + (size_t)sp * 16384;
                h8 tp[4];
#pragma unroll
                for (int i = 0; i < 4; ++i)
                    tp[i] = *(const h8*)(src + (size_t)(tid + i * 512) * 8);
#pragma unroll
                for (int i = 0; i < 4; ++i) {
                    int c = tid + i * 512;             // h8 index [0,2048)
                    *(h8*)(s_hd + (size_t)(c >> 7) * 1032 + (c & 127) * 8) = tp[i];
                }
            }
            __syncthreads();

            const half_t* ar = s_hd + (size_t)lo * 1032 + quad * 8;
            f4 acc = {0.f, 0.f, 0.f, 0.f}, acc2 = {0.f, 0.f, 0.f, 0.f};
            if (t == 1) {
#pragma unroll 8
                for (int ks = 0; ks < 32; ks += 2) {
                    h8 a0 = *(const h8*)(ar + ks * 32);
                    h8 a1 = *(const h8*)(ar + ks * 32 + 32);
                    acc = __builtin_amdgcn_mfma_f32_16x16x32_f16(a0, *(const h8*)(wb0 + ks * 32 + quad * 8), acc, 0, 0, 0);
                    acc2 = __builtin_amdgcn_mfma_f32_16x16x32_f16(a1, *(const h8*)(wb0 + ks * 32 + 32 + quad * 8), acc2, 0, 0, 0);
                }
            } else {
#pragma unroll
                for (int ks = 0; ks < 32; ks += 2) {
                    h8 a0 = *(const h8*)(ar + ks * 32);
                    h8 a1 = *(const h8*)(ar + ks * 32 + 32);
                    acc = __builtin_amdgcn_mfma_f32_16x16x32_f16(a0, wreg[ks], acc, 0, 0, 0);
                    acc2 = __builtin_amdgcn_mfma_f32_16x16x32_f16(a1, wreg[ks + 1], acc2, 0, 0, 0);
                }
            }
            const float bn = (t == 1) ? bias0 : biasE;
#pragma unroll
            for (int r = 0; r < 4; ++r) s_g[quad * 4 + r][wv * 16 + lo] = acc[r] + acc2[r] + bn;
            __syncthreads();
            {
                float gi = s_g[ub][ue * 4 + 0], gf = s_g[ub][ue * 4 + 1];
                float gg = s_g[ub][ue * 4 + 2], go = s_g[ub][ue * 4 + 3];
                float cn = sigm(gf) * s_c[ue][ub] + sigm(gi) * tanh_f(gg);
                s_c[ue][ub] = cn;
                s_hh[ue][ub] = (half_t)(sigm(go) * tanh_f(cn));
            }
            __syncthreads();
            if (tid < 64) {
                int b2 = tid >> 2, e8 = (tid & 3) * 8;
                union { half_t h[8]; u64 u[2]; } pk;
#pragma unroll
                for (int i = 0; i < 8; ++i) pk.h[i] = s_hh[e8 + i][b2];
                half_t* dst = hdG + (size_t)sn * 16384 + (size_t)b2 * 1024 + jj * 32 + e8;
                st_atom64(dst, pk.u[0]);
                st_atom64(dst + 4, pk.u[1]);
                asm volatile("s_waitcnt vmcnt(0)");
                if (tid < 34)
                    st_atom32(mbG + ((size_t)tid * 64 + jj), (unsigned)t);
            }
            sp = sn; sn += HOP; if (sn >= RING_D) sn -= RING_D;
        }
    } else {
        // ---------------- projection consumer blocks ----------------
        const int p = j - 64;
        const int g = p >> 1;                  // group
        const bool meld = ((p & 1) == 0);      // 0 = mel, 1 = gate
        half_t* hdG = hd + (size_t)g * ((size_t)RING_D * 16384);
        unsigned* mbG = mbD + (size_t)g * 34 * 64;
        const int cons = meld ? 32 : 33;       // consumer mailbox index
        const bool duty = meld || (wv == 0);
        const half_t* pw = meld ? (projwb + (size_t)(wv * 16 + lo) * 1024)
                                : (projg + (size_t)lo * 1024);
        const float biasP = meld ? projb[wv * 16 + lo] : gateb[0];

        h8 pwreg[32];
        if (duty) {
#pragma unroll
            for (int ks = 0; ks < 32; ++ks)
                pwreg[ks] = *(const h8*)(pw + ks * 32 + quad * 8);
        }
        if (tid < 32) s_len[tid] = mlens[tid];

        int spP = HOP;
        __syncthreads();

        for (int t = 1; t <= TMEL; ++t) {
            // wait for all 32 producers of slot spP (contains h_t)
            if (tid < 32) {
                const unsigned want = (unsigned)t;
                const unsigned* fp = mbG + (size_t)cons * 64 + tid;
                while (__hip_atomic_load(fp, __ATOMIC_RELAXED, __HIP_MEMORY_SCOPE_AGENT) < want)
                    __builtin_amdgcn_s_sleep(1);
            }
            __syncthreads();

            // cooperative cached load of the 32KB slot
            {
                const half_t* src = hdG + (size_t)spP * 16384;
                h8 tp[4];
#pragma unroll
                for (int i = 0; i < 4; ++i)
                    tp[i] = *(const h8*)(src + (size_t)(tid + i * 512) * 8);
#pragma unroll
                for (int i = 0; i < 4; ++i) {
                    int c = tid + i * 512;
                    *(h8*)(s_hd + (size_t)(c >> 7) * 1032 + (c & 127) * 8) = tp[i];
                }
            }
            __syncthreads();

            if (duty) {
                const half_t* ar = s_hd + (size_t)lo * 1032 + quad * 8;
                f4 accm = {0.f, 0.f, 0.f, 0.f}, accm2 = {0.f, 0.f, 0.f, 0.f};
#pragma unroll
                for (int ks = 0; ks < 32; ks += 2) {
                    h8 a0 = *(const h8*)(ar + ks * 32);
                    h8 a1 = *(const h8*)(ar + ks * 32 + 32);
                    accm = __builtin_amdgcn_mfma_f32_16x16x32_f16(a0, pwreg[ks], accm, 0, 0, 0);
                    accm2 = __builtin_amdgcn_mfma_f32_16x16x32_f16(a1, pwreg[ks + 1], accm2, 0, 0, 0);
                }
                accm[0] += accm2[0]; accm[1] += accm2[1];
                accm[2] += accm2[2]; accm[3] += accm2[3];
                const int pos = t - 1;
                if (meld) {
#pragma unroll
                    for (int r = 0; r < 4; ++r) {
                        int b = g * 16 + quad * 4 + r;
                        float v = accm[r] + biasP;
                        if (pos > s_len[b]) v = 0.f;
                        __builtin_nontemporal_store(v,
                            &out[(size_t)b * (TMEL * MM) + (size_t)pos * MM + wv * 16 + lo]);
                    }
                } else if (lo == 0) {
#pragma unroll
                    for (int r = 0; r < 4; ++r) {
                        int b = g * 16 + quad * 4 + r;
                        float v = accm[r] + biasP;
                        if (pos > s_len[b]) v = 1000.f;
                        __builtin_nontemporal_store(v, &out[GATE_OFF + (size_t)b * TMEL + pos]);
                    }
                }
            }
            __syncthreads();   // protect s_hd before next stage
            spP += HOP; if (spP >= RING_D) spP -= RING_D;
        }
    }
}

// ---------------------------------------------------------------------------

extern "C" void kernel_launch(void* const* d_in, const int* in_sizes, int n_in,
                              void* d_out, int out_size, void* d_ws, size_t ws_size,
                              hipStream_t stream) {
    const int* x = (const int*)d_in[0];
    const int* tlens = (const int*)d_in[1];
    const int* mlens = (const int*)d_in[3];
    const float* emb = (const float*)d_in[4];
    const float* c1w = (const float*)d_in[5];
    const float* c1b = (const float*)d_in[6];
    const float* bn1g = (const float*)d_in[7];
    const float* bn1b = (const float*)d_in[8];
    const float* c2w = (const float*)d_in[9];
    const float* c2b = (const float*)d_in[10];
    const float* bn2g = (const float*)d_in[11];
    const float* bn2b = (const float*)d_in[12];
    const float* wihf = (const float*)d_in[13];
    const float* whhf = (const float*)d_in[14];
    const float* bihf = (const float*)d_in[15];
    const float* bhhf = (const float*)d_in[16];
    const float* wihb = (const float*)d_in[17];
    const float* whhb = (const float*)d_in[18];
    const float* bihb = (const float*)d_in[19];
    const float* bhhb = (const float*)d_in[20];
    const float* dwih = (const float*)d_in[21];
    const float* dwhh = (const float*)d_in[22];
    const float* dbih = (const float*)d_in[23];
    const float* dbhh = (const float*)d_in[24];
    const float* projw = (const float*)d_in[25];
    const float* projb = (const float*)d_in[26];
    const float* gatew = (const float*)d_in[27];
    const float* gateb = (const float*)d_in[28];
    float* out = (float*)d_out;
    char* ws = (char*)d_ws;

    unsigned* mbE = (unsigned*)(ws + WS_MBE);
    unsigned* mbD = (unsigned*)(ws + WS_MBD);
    half_t* henc = (half_t*)(ws + WS_HENC);
    half_t* hd = (half_t*)(ws + WS_HD);
    half_t* bufX = (half_t*)(ws + WS_BUFX);
    half_t* bufY = (half_t*)(ws + WS_BUFY);
    float* convf = (float*)(ws + WS_CONVF);
    half_t* weff = (half_t*)(ws + WS_WEFF);
    half_t* w0 = (half_t*)(ws + WS_W0);
    half_t* wp1 = (half_t*)(ws + WS_WP1);
    half_t* wp2 = (half_t*)(ws + WS_WP2);
    float* meanb = (float*)(ws + WS_MEAN);
    float* rstdb = (float*)(ws + WS_RSTD);
    half_t* wihp = (half_t*)(ws + WS_WIHP);
    half_t* whhp = (half_t*)(ws + WS_WHHP);
    float* bsum = (float*)(ws + WS_BSUM);
    float* beff = (float*)(ws + WS_BEFF);
    float* b0 = (float*)(ws + WS_B0);
    half_t* projwb = (half_t*)(ws + WS_PROJW);
    half_t* projg = (half_t*)(ws + WS_PROJG);
    float* cel = (float*)(ws + WS_CEL);

    // zero mailboxes + encoder ring slot 0 (re-done every launch/replay)
    hipMemsetAsync(d_ws, 0, (size_t)WS_ZERO_BYTES, stream);

    // front-end
    k_embed<<<NROWS, 256, 0, stream>>>(x, emb, bufX);
    k_packconvw<<<(3 * EE * EE + 255) / 256, 256, 0, stream>>>(c1w, wp1);
    k_conv<<<dim3(128, 32), 256, 0, stream>>>(bufX, wp1, c1b, convf);
    k_bnstats<<<EE, 256, 0, stream>>>(convf, meanb, rstdb);
    k_bnapply<<<(NROWS * EE) / 256, 256, 0, stream>>>(convf, meanb, rstdb, bn1g, bn1b, bufY);
    k_packconvw<<<(3 * EE * EE + 255) / 256, 256, 0, stream>>>(c2w, wp2);
    k_conv<<<dim3(128, 32), 256, 0, stream>>>(bufY, wp2, c2b, convf);
    k_bnstats<<<EE, 256, 0, stream>>>(convf, meanb, rstdb);
    k_bnapply<<<(NROWS * EE) / 256, 256, 0, stream>>>(convf, meanb, rstdb, bn2g, bn2b, bufX);

    // encoder weight prep
    const int encTot = 2048 * 512;
    k_packrec<<<(encTot + 255) / 256, 256, 0, stream>>>(wihf, wihp, HH, 9, encTot);
    k_packrec<<<(encTot + 255) / 256, 256, 0, stream>>>(wihb, wihp + encTot, HH, 9, encTot);
    k_packrec<<<(encTot + 255) / 256, 256, 0, stream>>>(whhf, whhp, HH, 9, encTot);
    k_packrec<<<(encTot + 255) / 256, 256, 0, stream>>>(whhb, whhp + encTot, HH, 9, encTot);
    k_bsumenc<<<16, 256, 0, stream>>>(bihf, bhhf, bihb, bhhb, bsum);

    // persistent bidirectional encoder (writes dec ring slot 0s + cel)
    k_enc<<<64, 512, 0, stream>>>(bufX, wihp, whhp, bsum, tlens, henc, hd, cel, mbE);

    // decoder weight prep (into retired convf region)
    k_weff<<<dim3(4096, 4), 256, 0, stream>>>(dwhh, dwih, projw, weff, w0);
    k_bdec<<<16, 256, 0, stream>>>(dbih, dbhh, dwih, projb, beff, b0);
    k_cast<<<(MM * DD + 255) / 256, 256, 0, stream>>>(projw, projwb, MM * DD);
    k_projg<<<(16 * DD + 255) / 256, 256, 0, stream>>>(gatew, projg);

    // persistent decoder: 2 groups x (32 core + mel + gate)
    k_dec<<<68, 512, 0, stream>>>(weff, w0, beff, b0, projwb, projg, projb, gateb,
                                  mlens, cel, hd, out, mbD);

    // mask output
    k_mask<<<(B_ * TMEL + 255) / 256, 256, 0, stream>>>(mlens, out);

    (void)in_sizes; (void)n_in; (void)out_size; (void)ws_size;
}

// Round 11
// 4464.415 us; speedup vs baseline: 2.7970x; 1.0038x over previous
//
#include <hip/hip_runtime.h>

// ---------------------------------------------------------------------------
// TTS forward on MI355X.
//   embed -> conv1(+BN+ReLU) -> conv2(+BN+ReLU) -> persistent biLSTM encoder
//   -> W_eff fold -> persistent 800-step decoder LSTM + projection blocks
// Round 14: domain-split ENCODER (R13 pattern). Encoder = 4 independent
// exchange domains (dir x batch-half) x 16 blocks; each block owns 32
// h-elems x 16 batch -> per-wave tile identical to the verified R13 decoder
// (16 p-rows x 16 batch, weights in VGPRs). Slot 16KB, 16 producers,
// 16-wide fan-out/poll. Decoder = R13 verbatim (2 groups x 32 core blocks
// + mel + gate, 32KB slots, atomic-swap data + vmcnt ack + flag fan-out,
// poll-wave -> barrier -> contiguous coop load, 801-slot rings).
// ---------------------------------------------------------------------------

typedef float f4 __attribute__((ext_vector_type(4)));
typedef _Float16 h8 __attribute__((ext_vector_type(8)));
typedef _Float16 half_t;
typedef unsigned long long u64;

#define B_    32
#define LTXT  256
#define TMEL  800
#define EE    512
#define HH    512
#define DD    1024
#define MM    128
#define NROWS 8192          // B_*LTXT
#define GATE_OFF 3276800    // B_*TMEL*MM
#define MASK_OFF 3302400    // + B_*TMEL

#define RING_D 801          // decoder ring slots per group (32KB, never reused)
#define RING_E 257          // encoder ring slots per domain (16KB, never reused)
#define HOP    13           // coprime with both

// workspace offsets (bytes)
#define WS_MBE        0ull             // enc mailboxes: 4 dom x 16 cons x 64 u32 = 16 KiB
#define WS_MBD        16384ull         // dec mailboxes: 2 groups x 34 x 64 u32 (32 KiB rsvd)
#define WS_HENC       49152ull         // [RING_E][4 dom][16KB] = 16,842,752
#define WS_ZERO_BYTES 114688ull        // mailboxes + henc slot 0 (all 4 domains, 64KB)
#define WS_HD         16891904ull      // 2 groups * RING_D * 32768 = 52,494,336
#define WS_BUFX       69386240ull      // 8 MiB
#define WS_BUFY       77774848ull      // 8 MiB
#define WS_CONVF      86163456ull      // 16 MiB (reused by WEFF/W0 after convs)
#define WS_WEFF       86163456ull
#define WS_W0         94552064ull
#define WS_WP1        102940672ull
#define WS_WP2        104513536ull
#define WS_WIHP       106086400ull     // 4 MiB
#define WS_WHHP       110280704ull     // 4 MiB
#define WS_BSUM       114475008ull
#define WS_BEFF       114491392ull
#define WS_B0         114507776ull
#define WS_MEAN       114524160ull
#define WS_RSTD       114526208ull
#define WS_PROJW      114528256ull
#define WS_PROJG      114790400ull
#define WS_CEL        114823168ull
// total ~114.95 MB

__device__ __forceinline__ float sigm(float x) { return 1.f / (1.f + __expf(-x)); }
__device__ __forceinline__ float tanh_f(float x) {
    float e = __expf(2.f * x);
    return 1.f - 2.f / (e + 1.f);
}

// return-less atomic swap: executes at coherence point, line stays L3-resident
__device__ __forceinline__ void st_atom64(void* p, u64 v) {
    asm volatile("global_atomic_swap_x2 %0, %1, off" :: "v"(p), "v"(v) : "memory");
}
__device__ __forceinline__ void st_atom32(unsigned* p, unsigned v) {
    asm volatile("global_atomic_swap %0, %1, off" :: "v"(p), "v"(v) : "memory");
}

// ---------------- small prep kernels ----------------

__global__ void k_embed(const int* __restrict__ x, const float* __restrict__ emb,
                        half_t* __restrict__ out) {
    int row = blockIdx.x;
    int tok = x[row];
    const float* e = emb + (size_t)tok * EE;
    half_t* o = out + (size_t)row * EE;
    for (int c = threadIdx.x; c < EE; c += blockDim.x) o[c] = (half_t)e[c];
}

__global__ void k_packconvw(const float* __restrict__ w, half_t* __restrict__ wp) {
    int idx = blockIdx.x * 256 + threadIdx.x;
    if (idx >= 3 * EE * EE) return;
    int s = idx / (EE * EE);
    int rem = idx - s * EE * EE;
    int eo = rem >> 9, ei = rem & 511;
    wp[idx] = (half_t)w[(size_t)eo * (EE * 3) + ei * 3 + s];
}

__global__ __launch_bounds__(256) void k_conv(const half_t* __restrict__ A,
                                              const half_t* __restrict__ Wp,
                                              const float* __restrict__ bias,
                                              float* __restrict__ out) {
    const int nt = blockIdx.x, et = blockIdx.y;
    const int tid = threadIdx.x;
    const int wv = tid >> 6, l = tid & 63, quad = l >> 4, lo = l & 15;
    const int rowA = nt * 64 + wv * 16 + lo;
    const int eo = et * 16 + lo;
    f4 acc = {0.f, 0.f, 0.f, 0.f};
    for (int s = 0; s < 3; ++s) {
        int lsp = (rowA & 255) + s - 1;
        bool valid = (lsp >= 0) && (lsp < 256);
        int rs = rowA + s - 1;
        rs = rs < 0 ? 0 : (rs > NROWS - 1 ? NROWS - 1 : rs);
        const half_t* ab = A + (size_t)rs * EE;
        const half_t* wb = Wp + ((size_t)s * EE + eo) * EE;
#pragma unroll 4
        for (int ks = 0; ks < 16; ++ks) {
            h8 a = {0, 0, 0, 0, 0, 0, 0, 0};
            if (valid) a = *(const h8*)(ab + ks * 32 + quad * 8);
            h8 b = *(const h8*)(wb + ks * 32 + quad * 8);
            acc = __builtin_amdgcn_mfma_f32_16x16x32_f16(a, b, acc, 0, 0, 0);
        }
    }
    const int orow = nt * 64 + wv * 16 + quad * 4;
    const float bv = bias[eo];
#pragma unroll
    for (int r = 0; r < 4; ++r) out[(size_t)(orow + r) * EE + eo] = acc[r] + bv;
}

__global__ __launch_bounds__(256) void k_bnstats(const float* __restrict__ x,
                                                 float* __restrict__ mean,
                                                 float* __restrict__ rstd) {
    const int c = blockIdx.x;
    float s = 0.f, ss = 0.f;
    for (int n = threadIdx.x; n < NROWS; n += 256) {
        float v = x[(size_t)n * EE + c];
        s += v; ss += v * v;
    }
#pragma unroll
    for (int off = 32; off > 0; off >>= 1) { s += __shfl_down(s, off); ss += __shfl_down(ss, off); }
    __shared__ float as[4], ass[4];
    int wv = threadIdx.x >> 6;
    if ((threadIdx.x & 63) == 0) { as[wv] = s; ass[wv] = ss; }
    __syncthreads();
    if (threadIdx.x == 0) {
        float S = as[0] + as[1] + as[2] + as[3];
        float SS = ass[0] + ass[1] + ass[2] + ass[3];
        float m = S / (float)NROWS;
        float var = SS / (float)NROWS - m * m;
        mean[c] = m;
        rstd[c] = rsqrtf(var + 1e-5f);
    }
}

__global__ void k_bnapply(const float* __restrict__ x, const float* __restrict__ mean,
                          const float* __restrict__ rstd, const float* __restrict__ g,
                          const float* __restrict__ beta, half_t* __restrict__ out) {
    int idx = blockIdx.x * 256 + threadIdx.x;
    if (idx >= NROWS * EE) return;
    int c = idx & (EE - 1);
    float v = (x[idx] - mean[c]) * rstd[c] * g[c] + beta[c];
    out[idx] = (half_t)(v > 0.f ? v : 0.f);
}

__global__ void k_packrec(const float* __restrict__ src, half_t* __restrict__ dst,
                          int Hdim, int kshift, int total) {
    int idx = blockIdx.x * 256 + threadIdx.x;
    if (idx >= total) return;
    int p = idx >> kshift;
    int k = idx & ((1 << kshift) - 1);
    int he = p >> 2, g = p & 3;
    dst[idx] = (half_t)src[((size_t)g * Hdim + he) * (size_t)(1 << kshift) + k];
}

__global__ void k_bsumenc(const float* __restrict__ bf, const float* __restrict__ bhf,
                          const float* __restrict__ bb, const float* __restrict__ bhb,
                          float* __restrict__ bsum) {
    int p = blockIdx.x * 256 + threadIdx.x;
    if (p >= 4096) return;
    int dir = p >> 11, pp = p & 2047;
    int he = pp >> 2, g = pp & 3;
    int row = g * HH + he;
    bsum[p] = dir ? (bb[row] + bhb[row]) : (bf[row] + bhf[row]);
}

__global__ __launch_bounds__(256) void k_weff(const float* __restrict__ dwhh,
                                              const float* __restrict__ dwih,
                                              const float* __restrict__ projw,
                                              half_t* __restrict__ weff,
                                              half_t* __restrict__ w0) {
    int row = blockIdx.x;
    int k = blockIdx.y * 256 + threadIdx.x;
    float v = dwhh[(size_t)row * DD + k];
    float acc = v;
    for (int m = 0; m < MM; ++m) acc += dwih[(size_t)row * MM + m] * projw[(size_t)m * DD + k];
    int p = ((row & (DD - 1)) << 2) | (row >> 10);
    weff[(size_t)p * DD + k] = (half_t)acc;
    w0[(size_t)p * DD + k] = (half_t)v;
}

__global__ void k_bdec(const float* __restrict__ dbih, const float* __restrict__ dbhh,
                       const float* __restrict__ dwih, const float* __restrict__ projb,
                       float* __restrict__ beff, float* __restrict__ b0) {
    int p = blockIdx.x * 256 + threadIdx.x;
    if (p >= 4096) return;
    int he = p >> 2, g = p & 3;
    int row = g * DD + he;
    float bb = dbih[row] + dbhh[row];
    float acc = bb;
    for (int m = 0; m < MM; ++m) acc += dwih[(size_t)row * MM + m] * projb[m];
    b0[p] = bb;
    beff[p] = acc;
}

__global__ void k_cast(const float* __restrict__ src, half_t* __restrict__ dst, int n) {
    int idx = blockIdx.x * 256 + threadIdx.x;
    if (idx < n) dst[idx] = (half_t)src[idx];
}

__global__ void k_projg(const float* __restrict__ gw, half_t* __restrict__ pg) {
    int idx = blockIdx.x * 256 + threadIdx.x;
    if (idx >= 16 * DD) return;
    int row = idx >> 10, k = idx & (DD - 1);
    pg[idx] = (half_t)(row == 0 ? gw[k] : 0.f);
}

__global__ void k_mask(const int* __restrict__ lens, float* __restrict__ out) {
    int idx = blockIdx.x * 256 + threadIdx.x;
    if (idx >= B_ * TMEL) return;
    int b = idx / TMEL, t = idx - b * TMEL;
    out[MASK_OFF + idx] = (t > lens[b]) ? 1.f : 0.f;
}

// ---------------- persistent bidirectional encoder LSTM (domain-split) ----
// 64 blocks x 512 thr. Domain d=j>>4 (dir=d>>1, batch-group bg=d&1),
// jj=j&15 owns h-elems [32jj,32jj+32) x 16 batch. 8 waves, 1 tile/wave
// (16 p-rows x 16 batch), wih+whh in VGPRs (32 h8). Slot = [16 b][512] fp16
// = 16KB, layout [slot][4 dom][16KB] (slot 0 contiguous 64KB, pre-zeroed).
// Store: wave 0, 2 x 8B atomics/lane, vmcnt ack, lanes<16 fan flags.
// Poll: wave 1 lanes<16.
__global__ __launch_bounds__(512) void k_enc(const half_t* __restrict__ X,
                                             const half_t* __restrict__ wihp,
                                             const half_t* __restrict__ whhp,
                                             const float* __restrict__ bsum,
                                             const int* __restrict__ lens,
                                             half_t* __restrict__ henc,   // [RING_E][4][8192]
                                             half_t* __restrict__ hd,     // dec rings base
                                             float* __restrict__ cel,     // [32][1024]
                                             unsigned* __restrict__ mbE) { // [4][16][64]
    const int j = blockIdx.x;
    const int d = j >> 4, jj = j & 15;
    const int dir = d >> 1, bg = d & 1;
    const int tid = threadIdx.x;
    const int wv = tid >> 6, l = tid & 63, quad = l >> 4, lo = l & 15;
    const int ue = tid >> 4;   // h-elem within block [0,32)
    const int ub = tid & 15;   // batch within group [0,16)

    __shared__ half_t s_hd[16 * 520];
    __shared__ float s_g[16][129];
    __shared__ float s_c[32][16];
    __shared__ float s_h[32][16];
    __shared__ half_t s_hh[32][16];
    __shared__ int s_len[16];

    if (tid < 16) s_len[tid] = lens[bg * 16 + tid];
    s_c[ue][ub] = 0.f;
    s_h[ue][ub] = 0.f;

    const int pr = dir * 2048 + jj * 128 + wv * 16 + lo;
    const half_t* wih_b = wihp + (size_t)pr * 512;
    const half_t* whh_b = whhp + (size_t)pr * 512;
    const float bias_n = bsum[pr];

    h8 wihreg[16], whhreg[16];
#pragma unroll
    for (int ks = 0; ks < 16; ++ks) {
        wihreg[ks] = *(const h8*)(wih_b + ks * 32 + quad * 8);
        whhreg[ks] = *(const h8*)(whh_b + ks * 32 + quad * 8);
    }

    int sp = 0, sn = HOP;
    __syncthreads();

    for (int t = 0; t < 256; ++t) {
        // wait for the 16 producers of slot sp (slot 0 pre-zeroed => skip)
        if (t > 0) {
            if (wv == 1 && l < 16) {
                const unsigned want = (unsigned)t;
                const unsigned* fp = mbE + (size_t)(d * 16 + jj) * 64 + l;
                while (__hip_atomic_load(fp, __ATOMIC_RELAXED, __HIP_MEMORY_SCOPE_AGENT) < want)
                    __builtin_amdgcn_s_sleep(1);
            }
            __syncthreads();
        }

        // cooperative cached load of the domain's 16KB slot (2 x 16B/thread)
        const half_t* src = henc + ((size_t)sp * 4 + d) * 8192;
        h8 tmp0 = *(const h8*)(src + (size_t)(tid + 0 * 512) * 8);
        h8 tmp1 = *(const h8*)(src + (size_t)(tid + 1 * 512) * 8);

        // x-part MFMA overlaps the h loads (A rows = 16 batch, lane lo = batch)
        const int lb = s_len[lo];
        int tt = (dir == 0) ? t : (lb - 1 - t);
        tt = tt < 0 ? 0 : tt;
        const half_t* xr = X + ((size_t)(bg * 16 + lo) * 256 + tt) * 512;
        f4 accA = {0.f, 0.f, 0.f, 0.f}, accB = {0.f, 0.f, 0.f, 0.f};
#pragma unroll
        for (int ks = 0; ks < 16; ++ks) {
            h8 a = *(const h8*)(xr + ks * 32 + quad * 8);
            accA = __builtin_amdgcn_mfma_f32_16x16x32_f16(a, wihreg[ks], accA, 0, 0, 0);
        }

        // stage h into LDS ([16 b][512+8])
        {
            int c0 = tid;
            *(h8*)(s_hd + (size_t)(c0 >> 6) * 520 + (c0 & 63) * 8) = tmp0;
            int c1 = tid + 512;
            *(h8*)(s_hd + (size_t)(c1 >> 6) * 520 + (c1 & 63) * 8) = tmp1;
        }
        __syncthreads();

        const half_t* ar = s_hd + (size_t)lo * 520 + quad * 8;
#pragma unroll
        for (int ks = 0; ks < 16; ++ks) {
            h8 a = *(const h8*)(ar + ks * 32);
            accB = __builtin_amdgcn_mfma_f32_16x16x32_f16(a, whhreg[ks], accB, 0, 0, 0);
        }
#pragma unroll
        for (int r = 0; r < 4; ++r) s_g[quad * 4 + r][wv * 16 + lo] = accA[r] + accB[r] + bias_n;
        __syncthreads();
        {
            float gi = s_g[ub][ue * 4 + 0], gf = s_g[ub][ue * 4 + 1];
            float gg = s_g[ub][ue * 4 + 2], go = s_g[ub][ue * 4 + 3];
            float cn = sigm(gf) * s_c[ue][ub] + sigm(gi) * tanh_f(gg);
            float hn = sigm(go) * tanh_f(cn);
            if (t < s_len[ub]) { s_c[ue][ub] = cn; s_h[ue][ub] = hn; }
            s_hh[ue][ub] = (half_t)s_h[ue][ub];
        }
        __syncthreads();
        if (tid < 64 && t < 255) {
            int b2 = tid >> 2, e8 = (tid & 3) * 8;
            union { half_t h[8]; u64 u[2]; } pk;
#pragma unroll
            for (int i = 0; i < 8; ++i) pk.h[i] = s_hh[e8 + i][b2];
            half_t* dst = henc + ((size_t)sn * 4 + d) * 8192 + (size_t)b2 * 512 + jj * 32 + e8;
            st_atom64(dst, pk.u[0]);
            st_atom64(dst + 4, pk.u[1]);
            asm volatile("s_waitcnt vmcnt(0)");
            if (tid < 16)
                st_atom32(mbE + ((size_t)(d * 16 + tid) * 64 + jj), (unsigned)(t + 1));
        }
        if (t < 255) { sp = sn; sn += HOP; if (sn >= RING_E) sn -= RING_E; }
    }
    // epilogue: write dec ring slot 0 (grouped layout [bg][slot0][b][1024]) + cel
    hd[(size_t)bg * ((size_t)RING_D * 16384) + (size_t)ub * 1024
       + dir * 512 + jj * 32 + ue] = (half_t)s_h[ue][ub];
    cel[(size_t)(bg * 16 + ub) * 1024 + dir * 512 + jj * 32 + ue] = s_c[ue][ub];
}

// ---------------- persistent decoder LSTM (batch-split, R13 verbatim) -----
// Grid 68 x 512 thr. Two independent groups (batch 16 each):
//   Blocks 0..63: core; g=j>>5, jj=j&31 owns h-elems [32jj,32jj+32) for the
//     group's 16 batch items. 8 waves, 1 tile (16 rows x 16 batch) each,
//     32 MFMAs, Weff in VGPRs. Slot = [16 batch][1024] fp16 = 32KB.
//   Blocks 64..67: per group, mel block (all 128 mel rows) + gate block.
__global__ __launch_bounds__(512) void k_dec(const half_t* __restrict__ Weff,
                                             const half_t* __restrict__ W0,
                                             const float* __restrict__ beff,
                                             const float* __restrict__ b0,
                                             const half_t* __restrict__ projwb,
                                             const half_t* __restrict__ projg,
                                             const float* __restrict__ projb,
                                             const float* __restrict__ gateb,
                                             const int* __restrict__ mlens,
                                             const float* __restrict__ cel,
                                             half_t* __restrict__ hd,   // [2][RING_D][16][1024]
                                             float* __restrict__ out,
                                             unsigned* __restrict__ mbD) { // [2][34][64]
    const int j = blockIdx.x;
    const int tid = threadIdx.x;
    const int wv = tid >> 6, l = tid & 63, quad = l >> 4, lo = l & 15;

    __shared__ half_t s_hd[16 * 1032];
    __shared__ float s_g[16][129];
    __shared__ float s_c[32][16];
    __shared__ half_t s_hh[32][16];
    __shared__ int s_len[32];

    if (j < 64) {
        // ---------------- core recurrence block ----------------
        const int g = j >> 5, jj = j & 31;
        half_t* hdG = hd + (size_t)g * ((size_t)RING_D * 16384);
        unsigned* mbG = mbD + (size_t)g * 34 * 64;
        const int ue = tid >> 4;   // h-elem in block [0,32)
        const int ub = tid & 15;   // batch in group [0,16)

        s_c[ue][ub] = cel[(size_t)(g * 16 + ub) * 1024 + jj * 32 + ue];
        const int pr = jj * 128 + wv * 16 + lo;
        const float biasE = beff[pr], bias0 = b0[pr];
        const half_t* wbE = Weff + (size_t)pr * 1024;
        const half_t* wb0 = W0 + (size_t)pr * 1024;

        h8 wreg[32];
#pragma unroll
        for (int ks = 0; ks < 32; ++ks)
            wreg[ks] = *(const h8*)(wbE + ks * 32 + quad * 8);

        int sp = 0, sn = HOP;
        __syncthreads();

        for (int t = 1; t <= TMEL; ++t) {
            // wait for all 32 producers of slot sp (t==1: slot 0 from k_enc)
            if (t > 1) {
                if (tid >= 64 && tid < 96) {
                    const unsigned want = (unsigned)(t - 1);
                    const unsigned* fp = mbG + (size_t)jj * 64 + (tid - 64);
                    while (__hip_atomic_load(fp, __ATOMIC_RELAXED, __HIP_MEMORY_SCOPE_AGENT) < want)
                        __builtin_amdgcn_s_sleep(1);
                }
                __syncthreads();
            }

            // cooperative cached load of the 32KB slot (4 x 16B per thread)
            {
                const half_t* src = hdG + (size_t)sp * 16384;
                h8 tp[4];
#pragma unroll
                for (int i = 0; i < 4; ++i)
                    tp[i] = *(const h8*)(src + (size_t)(tid + i * 512) * 8);
#pragma unroll
                for (int i = 0; i < 4; ++i) {
                    int c = tid + i * 512;             // h8 index [0,2048)
                    *(h8*)(s_hd + (size_t)(c >> 7) * 1032 + (c & 127) * 8) = tp[i];
                }
            }
            __syncthreads();

            const half_t* ar = s_hd + (size_t)lo * 1032 + quad * 8;
            f4 acc = {0.f, 0.f, 0.f, 0.f}, acc2 = {0.f, 0.f, 0.f, 0.f};
            if (t == 1) {
#pragma unroll 8
                for (int ks = 0; ks < 32; ks += 2) {
                    h8 a0 = *(const h8*)(ar + ks * 32);
                    h8 a1 = *(const h8*)(ar + ks * 32 + 32);
                    acc = __builtin_amdgcn_mfma_f32_16x16x32_f16(a0, *(const h8*)(wb0 + ks * 32 + quad * 8), acc, 0, 0, 0);
                    acc2 = __builtin_amdgcn_mfma_f32_16x16x32_f16(a1, *(const h8*)(wb0 + ks * 32 + 32 + quad * 8), acc2, 0, 0, 0);
                }
            } else {
#pragma unroll
                for (int ks = 0; ks < 32; ks += 2) {
                    h8 a0 = *(const h8*)(ar + ks * 32);
                    h8 a1 = *(const h8*)(ar + ks * 32 + 32);
                    acc = __builtin_amdgcn_mfma_f32_16x16x32_f16(a0, wreg[ks], acc, 0, 0, 0);
                    acc2 = __builtin_amdgcn_mfma_f32_16x16x32_f16(a1, wreg[ks + 1], acc2, 0, 0, 0);
                }
            }
            const float bn = (t == 1) ? bias0 : biasE;
#pragma unroll
            for (int r = 0; r < 4; ++r) s_g[quad * 4 + r][wv * 16 + lo] = acc[r] + acc2[r] + bn;
            __syncthreads();
            {
                float gi = s_g[ub][ue * 4 + 0], gf = s_g[ub][ue * 4 + 1];
                float gg = s_g[ub][ue * 4 + 2], go = s_g[ub][ue * 4 + 3];
                float cn = sigm(gf) * s_c[ue][ub] + sigm(gi) * tanh_f(gg);
                s_c[ue][ub] = cn;
                s_hh[ue][ub] = (half_t)(sigm(go) * tanh_f(cn));
            }
            __syncthreads();
            if (tid < 64) {
                int b2 = tid >> 2, e8 = (tid & 3) * 8;
                union { half_t h[8]; u64 u[2]; } pk;
#pragma unroll
                for (int i = 0; i < 8; ++i) pk.h[i] = s_hh[e8 + i][b2];
                half_t* dst = hdG + (size_t)sn * 16384 + (size_t)b2 * 1024 + jj * 32 + e8;
                st_atom64(dst, pk.u[0]);
                st_atom64(dst + 4, pk.u[1]);
                asm volatile("s_waitcnt vmcnt(0)");
                if (tid < 34)
                    st_atom32(mbG + ((size_t)tid * 64 + jj), (unsigned)t);
            }
            sp = sn; sn += HOP; if (sn >= RING_D) sn -= RING_D;
        }
    } else {
        // ---------------- projection consumer blocks ----------------
        const int p = j - 64;
        const int g = p >> 1;                  // group
        const bool meld = ((p & 1) == 0);      // 0 = mel, 1 = gate
        half_t* hdG = hd + (size_t)g * ((size_t)RING_D * 16384);
        unsigned* mbG = mbD + (size_t)g * 34 * 64;
        const int cons = meld ? 32 : 33;       // consumer mailbox index
        const bool duty = meld || (wv == 0);
        const half_t* pw = meld ? (projwb + (size_t)(wv * 16 + lo) * 1024)
                                : (projg + (size_t)lo * 1024);
        const float biasP = meld ? projb[wv * 16 + lo] : gateb[0];

        h8 pwreg[32];
        if (duty) {
#pragma unroll
            for (int ks = 0; ks < 32; ++ks)
                pwreg[ks] = *(const h8*)(pw + ks * 32 + quad * 8);
        }
        if (tid < 32) s_len[tid] = mlens[tid];

        int spP = HOP;
        __syncthreads();

        for (int t = 1; t <= TMEL; ++t) {
            // wait for all 32 producers of slot spP (contains h_t)
            if (tid < 32) {
                const unsigned want = (unsigned)t;
                const unsigned* fp = mbG + (size_t)cons * 64 + tid;
                while (__hip_atomic_load(fp, __ATOMIC_RELAXED, __HIP_MEMORY_SCOPE_AGENT) < want)
                    __builtin_amdgcn_s_sleep(1);
            }
            __syncthreads();

            // cooperative cached load of the 32KB slot
            {
                const half_t* src = hdG + (size_t)spP * 16384;
                h8 tp[4];
#pragma unroll
                for (int i = 0; i < 4; ++i)
                    tp[i] = *(const h8*)(src + (size_t)(tid + i * 512) * 8);
#pragma unroll
                for (int i = 0; i < 4; ++i) {
                    int c = tid + i * 512;
                    *(h8*)(s_hd + (size_t)(c >> 7) * 1032 + (c & 127) * 8) = tp[i];
                }
            }
            __syncthreads();

            if (duty) {
                const half_t* ar = s_hd + (size_t)lo * 1032 + quad * 8;
                f4 accm = {0.f, 0.f, 0.f, 0.f}, accm2 = {0.f, 0.f, 0.f, 0.f};
#pragma unroll
                for (int ks = 0; ks < 32; ks += 2) {
                    h8 a0 = *(const h8*)(ar + ks * 32);
                    h8 a1 = *(const h8*)(ar + ks * 32 + 32);
                    accm = __builtin_amdgcn_mfma_f32_16x16x32_f16(a0, pwreg[ks], accm, 0, 0, 0);
                    accm2 = __builtin_amdgcn_mfma_f32_16x16x32_f16(a1, pwreg[ks + 1], accm2, 0, 0, 0);
                }
                accm[0] += accm2[0]; accm[1] += accm2[1];
                accm[2] += accm2[2]; accm[3] += accm2[3];
                const int pos = t - 1;
                if (meld) {
#pragma unroll
                    for (int r = 0; r < 4; ++r) {
                        int b = g * 16 + quad * 4 + r;
                        float v = accm[r] + biasP;
                        if (pos > s_len[b]) v = 0.f;
                        __builtin_nontemporal_store(v,
                            &out[(size_t)b * (TMEL * MM) + (size_t)pos * MM + wv * 16 + lo]);
                    }
                } else if (lo == 0) {
#pragma unroll
                    for (int r = 0; r < 4; ++r) {
                        int b = g * 16 + quad * 4 + r;
                        float v = accm[r] + biasP;
                        if (pos > s_len[b]) v = 1000.f;
                        __builtin_nontemporal_store(v, &out[GATE_OFF + (size_t)b * TMEL + pos]);
                    }
                }
            }
            __syncthreads();   // protect s_hd before next stage
            spP += HOP; if (spP >= RING_D) spP -= RING_D;
        }
    }
}

// ---------------------------------------------------------------------------

extern "C" void kernel_launch(void* const* d_in, const int* in_sizes, int n_in,
                              void* d_out, int out_size, void* d_ws, size_t ws_size,
                              hipStream_t stream) {
    const int* x = (const int*)d_in[0];
    const int* tlens = (const int*)d_in[1];
    const int* mlens = (const int*)d_in[3];
    const float* emb = (const float*)d_in[4];
    const float* c1w = (const float*)d_in[5];
    const float* c1b = (const float*)d_in[6];
    const float* bn1g = (const float*)d_in[7];
    const float* bn1b = (const float*)d_in[8];
    const float* c2w = (const float*)d_in[9];
    const float* c2b = (const float*)d_in[10];
    const float* bn2g = (const float*)d_in[11];
    const float* bn2b = (const float*)d_in[12];
    const float* wihf = (const float*)d_in[13];
    const float* whhf = (const float*)d_in[14];
    const float* bihf = (const float*)d_in[15];
    const float* bhhf = (const float*)d_in[16];
    const float* wihb = (const float*)d_in[17];
    const float* whhb = (const float*)d_in[18];
    const float* bihb = (const float*)d_in[19];
    const float* bhhb = (const float*)d_in[20];
    const float* dwih = (const float*)d_in[21];
    const float* dwhh = (const float*)d_in[22];
    const float* dbih = (const float*)d_in[23];
    const float* dbhh = (const float*)d_in[24];
    const float* projw = (const float*)d_in[25];
    const float* projb = (const float*)d_in[26];
    const float* gatew = (const float*)d_in[27];
    const float* gateb = (const float*)d_in[28];
    float* out = (float*)d_out;
    char* ws = (char*)d_ws;

    unsigned* mbE = (unsigned*)(ws + WS_MBE);
    unsigned* mbD = (unsigned*)(ws + WS_MBD);
    half_t* henc = (half_t*)(ws + WS_HENC);
    half_t* hd = (half_t*)(ws + WS_HD);
    half_t* bufX = (half_t*)(ws + WS_BUFX);
    half_t* bufY = (half_t*)(ws + WS_BUFY);
    float* convf = (float*)(ws + WS_CONVF);
    half_t* weff = (half_t*)(ws + WS_WEFF);
    half_t* w0 = (half_t*)(ws + WS_W0);
    half_t* wp1 = (half_t*)(ws + WS_WP1);
    half_t* wp2 = (half_t*)(ws + WS_WP2);
    float* meanb = (float*)(ws + WS_MEAN);
    float* rstdb = (float*)(ws + WS_RSTD);
    half_t* wihp = (half_t*)(ws + WS_WIHP);
    half_t* whhp = (half_t*)(ws + WS_WHHP);
    float* bsum = (float*)(ws + WS_BSUM);
    float* beff = (float*)(ws + WS_BEFF);
    float* b0 = (float*)(ws + WS_B0);
    half_t* projwb = (half_t*)(ws + WS_PROJW);
    half_t* projg = (half_t*)(ws + WS_PROJG);
    float* cel = (float*)(ws + WS_CEL);

    // zero mailboxes + encoder ring slot 0 (all 4 domains; re-done per launch)
    hipMemsetAsync(d_ws, 0, (size_t)WS_ZERO_BYTES, stream);

    // front-end
    k_embed<<<NROWS, 256, 0, stream>>>(x, emb, bufX);
    k_packconvw<<<(3 * EE * EE + 255) / 256, 256, 0, stream>>>(c1w, wp1);
    k_conv<<<dim3(128, 32), 256, 0, stream>>>(bufX, wp1, c1b, convf);
    k_bnstats<<<EE, 256, 0, stream>>>(convf, meanb, rstdb);
    k_bnapply<<<(NROWS * EE) / 256, 256, 0, stream>>>(convf, meanb, rstdb, bn1g, bn1b, bufY);
    k_packconvw<<<(3 * EE * EE + 255) / 256, 256, 0, stream>>>(c2w, wp2);
    k_conv<<<dim3(128, 32), 256, 0, stream>>>(bufY, wp2, c2b, convf);
    k_bnstats<<<EE, 256, 0, stream>>>(convf, meanb, rstdb);
    k_bnapply<<<(NROWS * EE) / 256, 256, 0, stream>>>(convf, meanb, rstdb, bn2g, bn2b, bufX);

    // encoder weight prep
    const int encTot = 2048 * 512;
    k_packrec<<<(encTot + 255) / 256, 256, 0, stream>>>(wihf, wihp, HH, 9, encTot);
    k_packrec<<<(encTot + 255) / 256, 256, 0, stream>>>(wihb, wihp + encTot, HH, 9, encTot);
    k_packrec<<<(encTot + 255) / 256, 256, 0, stream>>>(whhf, whhp, HH, 9, encTot);
    k_packrec<<<(encTot + 255) / 256, 256, 0, stream>>>(whhb, whhp + encTot, HH, 9, encTot);
    k_bsumenc<<<16, 256, 0, stream>>>(bihf, bhhf, bihb, bhhb, bsum);

    // persistent bidirectional encoder (4 domains; writes dec ring slot 0s + cel)
    k_enc<<<64, 512, 0, stream>>>(bufX, wihp, whhp, bsum, tlens, henc, hd, cel, mbE);

    // decoder weight prep (into retired convf region)
    k_weff<<<dim3(4096, 4), 256, 0, stream>>>(dwhh, dwih, projw, weff, w0);
    k_bdec<<<16, 256, 0, stream>>>(dbih, dbhh, dwih, projb, beff, b0);
    k_cast<<<(MM * DD + 255) / 256, 256, 0, stream>>>(projw, projwb, MM * DD);
    k_projg<<<(16 * DD + 255) / 256, 256, 0, stream>>>(gatew, projg);

    // persistent decoder: 2 groups x (32 core + mel + gate)
    k_dec<<<68, 512, 0, stream>>>(weff, w0, beff, b0, projwb, projg, projb, gateb,
                                  mlens, cel, hd, out, mbD);

    // mask output
    k_mask<<<(B_ * TMEL + 255) / 256, 256, 0, stream>>>(mlens, out);

    (void)in_sizes; (void)n_in; (void)out_size; (void)ws_size;
}